// Round 1
// baseline (8503.671 us; speedup 1.0000x reference)
//
#include <hip/hip_runtime.h>
#include <math.h>

#define BB 2
#define SS 4096
#define DD 1024
#define HH 8
#define DH 128
#define RR 2
#define CC 64
#define NBUCK 128
#define LL 2
#define FFD 4096
#define VV 258
#define RS (RR*SS)        // 8192
#define NC (RS/CC)        // 128
#define BH (BB*HH)        // 16
#define MROWS (BB*SS)     // 8192

// ---------------------------------------------------------------------------
// block-wide sum of two values (256 threads)
__device__ __forceinline__ void block_sum2(float& s, float& s2) {
  #pragma unroll
  for (int o = 1; o < 64; o <<= 1) { s += __shfl_xor(s, o); s2 += __shfl_xor(s2, o); }
  __shared__ float rs[4], rq[4];
  int wave = threadIdx.x >> 6;
  if ((threadIdx.x & 63) == 0) { rs[wave] = s; rq[wave] = s2; }
  __syncthreads();
  s  = rs[0] + rs[1] + rs[2] + rs[3];
  s2 = rq[0] + rq[1] + rq[2] + rq[3];
}

// ---------------------------------------------------------------------------
// x1 = x2 = x
__global__ __launch_bounds__(256) void init_x_kernel(const float* __restrict__ x,
                                                     float* __restrict__ x1,
                                                     float* __restrict__ x2) {
  size_t i = (size_t)blockIdx.x * 256 + threadIdx.x;
  float v = x[i];
  x1[i] = v; x2[i] = v;
}

// ---------------------------------------------------------------------------
// LayerNorm over D=1024, one block (256 thr) per row
__global__ __launch_bounds__(256) void ln_kernel(const float* __restrict__ x,
                                                 const float* __restrict__ g,
                                                 const float* __restrict__ bta,
                                                 float* __restrict__ out) {
  int row = blockIdx.x;
  int t = threadIdx.x;
  const float4* xr = (const float4*)(x + (size_t)row * DD);
  float4 xv = xr[t];
  float s  = xv.x + xv.y + xv.z + xv.w;
  float s2 = xv.x*xv.x + xv.y*xv.y + xv.z*xv.z + xv.w*xv.w;
  block_sum2(s, s2);
  float mu   = s * (1.0f / DD);
  float var  = fmaxf(s2 * (1.0f / DD) - mu * mu, 0.0f);
  float rstd = rsqrtf(var + 1e-12f);
  float4 gv = ((const float4*)g)[t];
  float4 bv = ((const float4*)bta)[t];
  float4 ov;
  ov.x = (xv.x - mu) * rstd * gv.x + bv.x;
  ov.y = (xv.y - mu) * rstd * gv.y + bv.y;
  ov.z = (xv.z - mu) * rstd * gv.z + bv.z;
  ov.w = (xv.w - mu) * rstd * gv.w + bv.w;
  ((float4*)(out + (size_t)row * DD))[t] = ov;
}

// LayerNorm over concat([x1,x2]) (2048), one block per row
__global__ __launch_bounds__(256) void ln_concat_kernel(const float* __restrict__ x1,
                                                        const float* __restrict__ x2,
                                                        const float* __restrict__ g,
                                                        const float* __restrict__ bta,
                                                        float* __restrict__ out) {
  int row = blockIdx.x;
  int t = threadIdx.x;
  float4 a = ((const float4*)(x1 + (size_t)row * DD))[t];
  float4 b = ((const float4*)(x2 + (size_t)row * DD))[t];
  float s  = a.x + a.y + a.z + a.w + b.x + b.y + b.z + b.w;
  float s2 = a.x*a.x + a.y*a.y + a.z*a.z + a.w*a.w
           + b.x*b.x + b.y*b.y + b.z*b.z + b.w*b.w;
  block_sum2(s, s2);
  float mu   = s * (1.0f / (2*DD));
  float var  = fmaxf(s2 * (1.0f / (2*DD)) - mu * mu, 0.0f);
  float rstd = rsqrtf(var + 1e-12f);
  float4 g1 = ((const float4*)g)[t];
  float4 b1v = ((const float4*)bta)[t];
  float4 g2 = ((const float4*)g)[256 + t];
  float4 b2v = ((const float4*)bta)[256 + t];
  float4 o1, o2;
  o1.x = (a.x - mu)*rstd*g1.x + b1v.x;  o1.y = (a.y - mu)*rstd*g1.y + b1v.y;
  o1.z = (a.z - mu)*rstd*g1.z + b1v.z;  o1.w = (a.w - mu)*rstd*g1.w + b1v.w;
  o2.x = (b.x - mu)*rstd*g2.x + b2v.x;  o2.y = (b.y - mu)*rstd*g2.y + b2v.y;
  o2.z = (b.z - mu)*rstd*g2.z + b2v.z;  o2.w = (b.w - mu)*rstd*g2.w + b2v.w;
  float4* orow = (float4*)(out + (size_t)row * (2*DD));
  orow[t] = o1;
  orow[256 + t] = o2;
}

// ---------------------------------------------------------------------------
// Tiled fp32 GEMM: C = A(MxK) @ B(KxN) [+bias][relu][+=]
// 64x64 tile, 256 threads, 4x4 micro-tile, K-step 16
template<typename AccT, bool BIAS, bool RELU, bool ACCUM>
__global__ __launch_bounds__(256) void sgemm_kernel(const float* __restrict__ A,
                                                    const float* __restrict__ Bm,
                                                    const float* __restrict__ bias,
                                                    float* __restrict__ Cm,
                                                    int M, int N, int K) {
  __shared__ float As[16][68];
  __shared__ float Bs[16][68];
  int tid = threadIdx.x;
  int tx = tid & 15, ty = tid >> 4;
  int row0 = blockIdx.y * 64, col0 = blockIdx.x * 64;
  AccT acc[4][4];
  #pragma unroll
  for (int i = 0; i < 4; i++)
    #pragma unroll
    for (int j = 0; j < 4; j++) acc[i][j] = (AccT)0;

  for (int k0 = 0; k0 < K; k0 += 16) {
    #pragma unroll
    for (int i = 0; i < 4; i++) {
      int idx = (i << 8) + tid;
      int r = idx >> 4, kk = idx & 15;
      As[kk][r] = A[(size_t)(row0 + r) * K + k0 + kk];
    }
    #pragma unroll
    for (int i = 0; i < 4; i++) {
      int idx = (i << 8) + tid;
      int kk = idx >> 6, c = idx & 63;
      int col = col0 + c;
      Bs[kk][c] = (col < N) ? Bm[(size_t)(k0 + kk) * N + col] : 0.0f;
    }
    __syncthreads();
    #pragma unroll
    for (int kk = 0; kk < 16; kk++) {
      float a0 = As[kk][ty*4+0], a1 = As[kk][ty*4+1], a2 = As[kk][ty*4+2], a3 = As[kk][ty*4+3];
      float b0 = Bs[kk][tx*4+0], b1 = Bs[kk][tx*4+1], b2 = Bs[kk][tx*4+2], b3 = Bs[kk][tx*4+3];
      acc[0][0] += (AccT)a0*(AccT)b0; acc[0][1] += (AccT)a0*(AccT)b1; acc[0][2] += (AccT)a0*(AccT)b2; acc[0][3] += (AccT)a0*(AccT)b3;
      acc[1][0] += (AccT)a1*(AccT)b0; acc[1][1] += (AccT)a1*(AccT)b1; acc[1][2] += (AccT)a1*(AccT)b2; acc[1][3] += (AccT)a1*(AccT)b3;
      acc[2][0] += (AccT)a2*(AccT)b0; acc[2][1] += (AccT)a2*(AccT)b1; acc[2][2] += (AccT)a2*(AccT)b2; acc[2][3] += (AccT)a2*(AccT)b3;
      acc[3][0] += (AccT)a3*(AccT)b0; acc[3][1] += (AccT)a3*(AccT)b1; acc[3][2] += (AccT)a3*(AccT)b2; acc[3][3] += (AccT)a3*(AccT)b3;
    }
    __syncthreads();
  }
  #pragma unroll
  for (int i = 0; i < 4; i++) {
    int row = row0 + ty*4 + i;
    #pragma unroll
    for (int j = 0; j < 4; j++) {
      int col = col0 + tx*4 + j;
      if (col < N) {
        float val = (float)acc[i][j];
        if (BIAS) val += bias[col];
        if (RELU) val = fmaxf(val, 0.0f);
        size_t off = (size_t)row * N + col;
        if (ACCUM) Cm[off] += val; else Cm[off] = val;
      }
    }
  }
}

// ---------------------------------------------------------------------------
// buckets: one wave per (b,h,s); fp64 accumulation for argmax stability
__global__ __launch_bounds__(64) void bucket_kernel(const float* __restrict__ qk,
                                                    const float* __restrict__ rot,
                                                    int* __restrict__ ids) {
  int blk = blockIdx.x;                // (b*H+h)*S + s
  int s = blk & (SS - 1);
  int bh = blk >> 12;
  int b = bh >> 3, h = bh & 7;
  int lane = threadIdx.x;
  __shared__ float qv[DH];
  const float* qrow = qk + ((size_t)(b * SS + s)) * DD + h * DH;
  qv[lane] = qrow[lane];
  qv[lane + 64] = qrow[lane + 64];
  __syncthreads();
  const float* rh = rot + (size_t)h * (DH * RR * 64);
  for (int r = 0; r < RR; r++) {
    const float* rp = rh + r * 64 + lane;   // [d*128 + r*64 + lane]
    double acc = 0.0;
    #pragma unroll 4
    for (int d = 0; d < DH; d++) acc += (double)qv[d] * (double)rp[(size_t)d * 128];
    double bv; int bi;
    if (acc >= -acc) { bv = acc; bi = lane; } else { bv = -acc; bi = 64 + lane; }
    #pragma unroll
    for (int o = 1; o < 64; o <<= 1) {
      double ov = __shfl_xor(bv, o);
      int oi = __shfl_xor(bi, o);
      if (ov > bv || (ov == bv && oi < bi)) { bv = ov; bi = oi; }
    }
    if (lane == 0) ids[((size_t)bh * RR + r) * SS + s] = bi + r * NBUCK;
  }
}

// ---------------------------------------------------------------------------
// stable counting sort over 256 bucket ids per (b,h): reproduces argsort(ids*S+pos)
__global__ __launch_bounds__(256) void sort_kernel(const int* __restrict__ ids,
                                                   int* __restrict__ orig,
                                                   int* __restrict__ undo) {
  int bh = blockIdx.x;
  int t = threadIdx.x;              // bucket id 0..255
  int r = t >> 7;
  const int* idp = ids + ((size_t)bh * RR + r) * SS;
  __shared__ int offs[256];
  int c = 0;
  for (int s = 0; s < SS; s++) c += (idp[s] == t) ? 1 : 0;
  offs[t] = c;
  __syncthreads();
  if (t == 0) {
    int acc = 0;
    for (int i = 0; i < 256; i++) { int cc = offs[i]; offs[i] = acc; acc += cc; }
  }
  __syncthreads();
  int o = offs[t];
  for (int s = 0; s < SS; s++) {
    if (idp[s] == t) {
      orig[(size_t)bh * RS + o] = s;
      undo[(size_t)bh * RS + r * SS + s] = o;
      o++;
    }
  }
}

// ---------------------------------------------------------------------------
// per-sorted-key normalization scale: rsqrt(mean(sq^2)+1e-6)/sqrt(Dh)
__global__ __launch_bounds__(256) void rnorm_kernel(const float* __restrict__ qk,
                                                    const int* __restrict__ orig,
                                                    float* __restrict__ rno) {
  int idx = blockIdx.x * 4 + (threadIdx.x >> 6);   // key index over BH*RS
  int lane = threadIdx.x & 63;
  int bh = idx >> 13;
  int k = idx & (RS - 1);
  int b = bh >> 3, h = bh & 7;
  int s = orig[(size_t)bh * RS + k];
  const float* row = qk + ((size_t)(b * SS + s)) * DD + h * DH;
  float x0 = row[lane], x1 = row[lane + 64];
  float ss = x0 * x0 + x1 * x1;
  #pragma unroll
  for (int o = 1; o < 64; o <<= 1) ss += __shfl_xor(ss, o);
  if (lane == 0)
    rno[(size_t)bh * RS + k] = rsqrtf(ss * (1.0f / DH) + 1e-6f) * 0.08838834764831845f;
}

// ---------------------------------------------------------------------------
// chunked attention: one block (256 thr) per (b,h,chunk)
__global__ __launch_bounds__(256) void attn_kernel(const float* __restrict__ qk,
                                                   const float* __restrict__ v,
                                                   const int* __restrict__ orig,
                                                   const float* __restrict__ rno,
                                                   float* __restrict__ osort,
                                                   float* __restrict__ lg) {
  __shared__ float qs[64 * 128];   // queries, later probs
  __shared__ float kb[128 * 64];   // key half-tiles (swizzled), later value half-tiles
  int blk = blockIdx.x;
  int n = blk & (NC - 1);
  int bh = blk >> 7;
  int b = bh >> 3, h = bh & 7;
  int pn = (n + NC - 1) & (NC - 1);
  int tid = threadIdx.x;
  int wave = tid >> 6, lane = tid & 63;
  const int* origp = orig + (size_t)bh * RS;
  const float* rnp = rno + (size_t)bh * RS;
  const size_t base = (size_t)b * SS * DD + (size_t)h * DH;

  // stage queries (unnormalized)
  for (int idx = tid; idx < 64 * 128; idx += 256) {
    int c = idx >> 7, d = idx & 127;
    qs[idx] = qk[base + (size_t)origp[n * 64 + c] * DD + d];
  }
  // stage keys half A (prev chunk), normalized; xor-swizzled [d][j]
  for (int idx = tid; idx < 64 * 128; idx += 256) {
    int j = idx >> 7, d = idx & 127;
    int kidx = pn * 64 + j;
    kb[d * 64 + (j ^ (d & 63))] = qk[base + (size_t)origp[kidx] * DD + d] * rnp[kidx];
  }
  int kpA = origp[pn * 64 + lane];
  int kpB = origp[n * 64 + lane];
  int qp_reg = origp[n * 64 + wave * 16 + (lane & 15)];
  float accA[16], accB[16];
  #pragma unroll
  for (int c = 0; c < 16; c++) { accA[c] = 0.f; accB[c] = 0.f; }
  __syncthreads();

  const float* qw = qs + wave * (16 * 128);
  #pragma unroll 2
  for (int d = 0; d < 128; d++) {
    float kv0 = kb[d * 64 + (lane ^ (d & 63))];
    #pragma unroll
    for (int c = 0; c < 16; c++) accA[c] += qw[c * 128 + d] * kv0;
  }
  __syncthreads();
  // stage keys half B (current chunk)
  for (int idx = tid; idx < 64 * 128; idx += 256) {
    int j = idx >> 7, d = idx & 127;
    int kidx = n * 64 + j;
    kb[d * 64 + (j ^ (d & 63))] = qk[base + (size_t)origp[kidx] * DD + d] * rnp[kidx];
  }
  __syncthreads();
  #pragma unroll 2
  for (int d = 0; d < 128; d++) {
    float kv0 = kb[d * 64 + (lane ^ (d & 63))];
    #pragma unroll
    for (int c = 0; c < 16; c++) accB[c] += qw[c * 128 + d] * kv0;
  }

  // masked softmax per query (keys distributed over lanes: pair {lane, 64+lane})
  float pA[16], pB[16];
  #pragma unroll
  for (int ci = 0; ci < 16; ci++) {
    int qp = __shfl(qp_reg, ci);
    float sA = (kpA > qp) ? -1000000000.0f : ((kpA == qp) ? -100000.0f : accA[ci]);
    float sB = (kpB > qp) ? -1000000000.0f : ((kpB == qp) ? -100000.0f : accB[ci]);
    float m = fmaxf(sA, sB);
    #pragma unroll
    for (int o = 1; o < 64; o <<= 1) m = fmaxf(m, __shfl_xor(m, o));
    float eA = __expf(sA - m), eB = __expf(sB - m);
    float sum = eA + eB;
    #pragma unroll
    for (int o = 1; o < 64; o <<= 1) sum += __shfl_xor(sum, o);
    pA[ci] = eA / sum;
    pB[ci] = eB / sum;
    if (lane == 0) lg[(size_t)bh * RS + n * 64 + wave * 16 + ci] = m + __logf(sum);
  }
  __syncthreads();   // everyone done reading qs / kb

  // probs -> qs (own wave's rows only)
  #pragma unroll
  for (int ci = 0; ci < 16; ci++) {
    qs[(wave * 16 + ci) * 128 + lane] = pA[ci];
    qs[(wave * 16 + ci) * 128 + 64 + lane] = pB[ci];
  }
  // stage values half A: [j][d]
  for (int idx = tid; idx < 64 * 128; idx += 256) {
    int j = idx >> 7, d = idx & 127;
    kb[j * 128 + d] = v[base + (size_t)origp[pn * 64 + j] * DD + d];
  }
  __syncthreads();
  float o0[16], o1[16];
  #pragma unroll
  for (int c = 0; c < 16; c++) { o0[c] = 0.f; o1[c] = 0.f; }
  #pragma unroll 2
  for (int j = 0; j < 64; j++) {
    float v0 = kb[j * 128 + lane];
    float v1 = kb[j * 128 + 64 + lane];
    #pragma unroll
    for (int c = 0; c < 16; c++) {
      float p = qw[c * 128 + j];
      o0[c] += p * v0; o1[c] += p * v1;
    }
  }
  __syncthreads();
  // stage values half B
  for (int idx = tid; idx < 64 * 128; idx += 256) {
    int j = idx >> 7, d = idx & 127;
    kb[j * 128 + d] = v[base + (size_t)origp[n * 64 + j] * DD + d];
  }
  __syncthreads();
  #pragma unroll 2
  for (int j = 0; j < 64; j++) {
    float v0 = kb[j * 128 + lane];
    float v1 = kb[j * 128 + 64 + lane];
    #pragma unroll
    for (int c = 0; c < 16; c++) {
      float p = qw[c * 128 + 64 + j];
      o0[c] += p * v0; o1[c] += p * v1;
    }
  }
  #pragma unroll
  for (int ci = 0; ci < 16; ci++) {
    size_t off = ((size_t)bh * RS + n * 64 + wave * 16 + ci) * DH;
    osort[off + lane] = o0[ci];
    osort[off + 64 + lane] = o1[ci];
  }
}

// ---------------------------------------------------------------------------
// unsort + softmax-over-rounds combine -> attn output (B,S,H*Dh)
__global__ __launch_bounds__(256) void unsort_kernel(const float* __restrict__ osort,
                                                     const float* __restrict__ lg,
                                                     const int* __restrict__ undo,
                                                     float* __restrict__ attn) {
  int gid = blockIdx.x * 4 + (threadIdx.x >> 6);   // (b*H+h)*S + s
  int lane = threadIdx.x & 63;
  int bh = gid >> 12;
  int s = gid & (SS - 1);
  int b = bh >> 3, h = bh & 7;
  int k0 = undo[(size_t)bh * RS + s];
  int k1 = undo[(size_t)bh * RS + SS + s];
  float l0 = lg[(size_t)bh * RS + k0], l1 = lg[(size_t)bh * RS + k1];
  float m = fmaxf(l0, l1);
  float e0 = __expf(l0 - m), e1 = __expf(l1 - m);
  float inv = 1.0f / (e0 + e1);
  float w0 = e0 * inv, w1 = e1 * inv;
  const float* r0 = osort + ((size_t)bh * RS + k0) * DH;
  const float* r1 = osort + ((size_t)bh * RS + k1) * DH;
  float* outp = attn + ((size_t)(b * SS + s)) * DD + h * DH;
  outp[lane]      = w0 * r0[lane]      + w1 * r1[lane];
  outp[lane + 64] = w0 * r0[lane + 64] + w1 * r1[lane + 64];
}

// ---------------------------------------------------------------------------
// softmax over batch axis (B=2)
__global__ __launch_bounds__(256) void softmax_b_kernel(const float* __restrict__ logits,
                                                        float* __restrict__ out) {
  int i = blockIdx.x * 256 + threadIdx.x;   // over S*V
  if (i >= SS * VV) return;
  int s = i / VV, vv = i - s * VV;
  float l0 = logits[(size_t)s * VV + vv];
  float l1 = logits[(size_t)(SS + s) * VV + vv];
  float m = fmaxf(l0, l1);
  float e0 = __expf(l0 - m), e1 = __expf(l1 - m);
  float inv = 1.0f / (e0 + e1);
  out[(size_t)s * VV + vv] = e0 * inv;
  out[(size_t)(SS + s) * VV + vv] = e1 * inv;
}

// ---------------------------------------------------------------------------
extern "C" void kernel_launch(void* const* d_in, const int* in_sizes, int n_in,
                              void* d_out, int out_size, void* d_ws, size_t ws_size,
                              hipStream_t stream) {
  (void)in_sizes; (void)n_in; (void)out_size; (void)ws_size;
  const float* x     = (const float*)d_in[0];
  const float* ln1_g = (const float*)d_in[1];
  const float* ln1_b = (const float*)d_in[2];
  const float* Wqk   = (const float*)d_in[3];
  const float* Wv    = (const float*)d_in[4];
  const float* Wo    = (const float*)d_in[5];
  const float* rot   = (const float*)d_in[6];
  const float* ln2_g = (const float*)d_in[7];
  const float* ln2_b = (const float*)d_in[8];
  const float* W1    = (const float*)d_in[9];
  const float* b1    = (const float*)d_in[10];
  const float* W2    = (const float*)d_in[11];
  const float* b2    = (const float*)d_in[12];
  const float* lnf_g = (const float*)d_in[13];
  const float* lnf_b = (const float*)d_in[14];
  const float* Wout  = (const float*)d_in[15];
  const float* bout  = (const float*)d_in[16];

  const size_t NX = (size_t)MROWS * DD;          // 8,388,608
  float* ws = (float*)d_ws;
  float* x1    = ws;
  float* x2    = x1 + NX;
  float* h     = x2 + NX;
  float* qkb   = h + NX;
  float* vb    = qkb + NX;
  float* osort = vb + NX;                        // 16,777,216
  float* lgb   = osort + (size_t)BH * RS * DH;
  float* rno   = lgb + (size_t)BH * RS;
  int*   orig  = (int*)(rno + (size_t)BH * RS);
  int*   undo  = orig + (size_t)BH * RS;
  int*   ids   = undo + (size_t)BH * RS;
  // aliases (time-disjoint):
  float* ff     = qkb;   // 33.5M floats over qk+v+osort, FFN only
  float* hcat   = qkb;   // 16.8M floats over qk+v, final only
  float* logits = h;     // 2.1M floats, final only

  init_x_kernel<<<(int)(NX / 256), 256, 0, stream>>>(x, x1, x2);

  for (int l = 0; l < LL; l++) {
    ln_kernel<<<MROWS, 256, 0, stream>>>(x2, ln1_g + l*DD, ln1_b + l*DD, h);
    // qk projection: fp64 accumulation (bucket-critical)
    sgemm_kernel<double,false,false,false><<<dim3(16,128), 256, 0, stream>>>(
        h, Wqk + (size_t)l*DD*DD, nullptr, qkb, MROWS, DD, DD);
    sgemm_kernel<float,false,false,false><<<dim3(16,128), 256, 0, stream>>>(
        h, Wv + (size_t)l*DD*DD, nullptr, vb, MROWS, DD, DD);
    bucket_kernel<<<BB*HH*SS, 64, 0, stream>>>(qkb, rot + (size_t)l*HH*DH*RR*64, ids);
    sort_kernel<<<BH, 256, 0, stream>>>(ids, orig, undo);
    rnorm_kernel<<<BH*RS/4, 256, 0, stream>>>(qkb, orig, rno);
    attn_kernel<<<BH*NC, 256, 0, stream>>>(qkb, vb, orig, rno, osort, lgb);
    unsort_kernel<<<BH*SS/4, 256, 0, stream>>>(osort, lgb, undo, h);
    sgemm_kernel<float,false,false,true><<<dim3(16,128), 256, 0, stream>>>(
        h, Wo + (size_t)l*DD*DD, nullptr, x1, MROWS, DD, DD);
    // FFN
    ln_kernel<<<MROWS, 256, 0, stream>>>(x1, ln2_g + l*DD, ln2_b + l*DD, h);
    sgemm_kernel<float,true,true,false><<<dim3(64,128), 256, 0, stream>>>(
        h, W1 + (size_t)l*DD*FFD, b1 + (size_t)l*FFD, ff, MROWS, FFD, DD);
    sgemm_kernel<float,true,false,true><<<dim3(16,128), 256, 0, stream>>>(
        ff, W2 + (size_t)l*FFD*DD, b2 + (size_t)l*DD, x2, MROWS, DD, FFD);
  }

  ln_concat_kernel<<<MROWS, 256, 0, stream>>>(x1, x2, lnf_g, lnf_b, hcat);
  sgemm_kernel<float,true,false,false><<<dim3((VV+63)/64, 128), 256, 0, stream>>>(
      hcat, Wout, bout, logits, MROWS, VV, 2*DD);
  softmax_b_kernel<<<(SS*VV + 255)/256, 256, 0, stream>>>(logits, (float*)d_out);
}

// Round 4
// 4197.314 us; speedup vs baseline: 2.0260x; 2.0260x over previous
//
#include <hip/hip_runtime.h>
#include <hip/hip_bf16.h>
#include <math.h>

#define BB 2
#define SS 4096
#define DD 1024
#define HH 8
#define DH 128
#define RR 2
#define CC 64
#define NBUCK 128
#define LL 2
#define FFD 4096
#define VV 258
#define VP 384            // padded vocab for head GEMM (multiple of 128)
#define RS (RR*SS)        // 8192
#define NC (RS/CC)        // 128
#define BH (BB*HH)        // 16
#define MROWS (BB*SS)     // 8192

typedef __attribute__((ext_vector_type(8))) short v8s;
typedef __attribute__((ext_vector_type(4))) float v4f;

// ---------------------------------------------------------------------------
__device__ __forceinline__ unsigned short f2bf(float f) {
  unsigned int u = __float_as_uint(f);
  u = (u + 0x7FFFu + ((u >> 16) & 1u)) >> 16;     // round-to-nearest-even
  return (unsigned short)u;
}
__device__ __forceinline__ float bf2f(unsigned short h) {
  return __uint_as_float(((unsigned int)h) << 16);
}
__device__ __forceinline__ unsigned int pack_bf2(float a, float b) {
  __hip_bfloat162 h = __float22bfloat162_rn(make_float2(a, b));
  union { __hip_bfloat162 h2; unsigned int u; } cv;
  cv.h2 = h;
  return cv.u;
}
__device__ __forceinline__ float lo_f(unsigned int u) { return __uint_as_float(u << 16); }
__device__ __forceinline__ float hi_f(unsigned int u) { return __uint_as_float(u & 0xFFFF0000u); }

__device__ __forceinline__ void gld16(const void* g, void* l) {
  __builtin_amdgcn_global_load_lds((const __attribute__((address_space(1))) void*)g,
                                   (__attribute__((address_space(3))) void*)l, 16, 0, 0);
}

// ---------------------------------------------------------------------------
__device__ __forceinline__ void block_sum2(float& s, float& s2) {
  #pragma unroll
  for (int o = 1; o < 64; o <<= 1) { s += __shfl_xor(s, o); s2 += __shfl_xor(s2, o); }
  __shared__ float rs[4], rq[4];
  int wave = threadIdx.x >> 6;
  if ((threadIdx.x & 63) == 0) { rs[wave] = s; rq[wave] = s2; }
  __syncthreads();
  s  = rs[0] + rs[1] + rs[2] + rs[3];
  s2 = rq[0] + rq[1] + rq[2] + rq[3];
}

// ---------------------------------------------------------------------------
__global__ __launch_bounds__(256) void init_x_kernel(const float* __restrict__ x,
                                                     float* __restrict__ x1,
                                                     float* __restrict__ x2) {
  size_t i = (size_t)blockIdx.x * 256 + threadIdx.x;
  float v = x[i];
  x1[i] = v; x2[i] = v;
}

// ---------------------------------------------------------------------------
// LayerNorm over D=1024, fp32 out
__global__ __launch_bounds__(256) void ln_kernel(const float* __restrict__ x,
                                                 const float* __restrict__ g,
                                                 const float* __restrict__ bta,
                                                 float* __restrict__ out) {
  int row = blockIdx.x;
  int t = threadIdx.x;
  float4 xv = ((const float4*)(x + (size_t)row * DD))[t];
  float s  = xv.x + xv.y + xv.z + xv.w;
  float s2 = xv.x*xv.x + xv.y*xv.y + xv.z*xv.z + xv.w*xv.w;
  block_sum2(s, s2);
  float mu   = s * (1.0f / DD);
  float var  = fmaxf(s2 * (1.0f / DD) - mu * mu, 0.0f);
  float rstd = rsqrtf(var + 1e-12f);
  float4 gv = ((const float4*)g)[t];
  float4 bv = ((const float4*)bta)[t];
  float4 ov;
  ov.x = (xv.x - mu) * rstd * gv.x + bv.x;
  ov.y = (xv.y - mu) * rstd * gv.y + bv.y;
  ov.z = (xv.z - mu) * rstd * gv.z + bv.z;
  ov.w = (xv.w - mu) * rstd * gv.w + bv.w;
  ((float4*)(out + (size_t)row * DD))[t] = ov;
}

// LayerNorm over concat([x1,x2]) (2048), fp32 out
__global__ __launch_bounds__(256) void ln_concat_kernel(const float* __restrict__ x1,
                                                        const float* __restrict__ x2,
                                                        const float* __restrict__ g,
                                                        const float* __restrict__ bta,
                                                        float* __restrict__ out) {
  int row = blockIdx.x;
  int t = threadIdx.x;
  float4 a = ((const float4*)(x1 + (size_t)row * DD))[t];
  float4 b = ((const float4*)(x2 + (size_t)row * DD))[t];
  float s  = a.x + a.y + a.z + a.w + b.x + b.y + b.z + b.w;
  float s2 = a.x*a.x + a.y*a.y + a.z*a.z + a.w*a.w
           + b.x*b.x + b.y*b.y + b.z*b.z + b.w*b.w;
  block_sum2(s, s2);
  float mu   = s * (1.0f / (2*DD));
  float var  = fmaxf(s2 * (1.0f / (2*DD)) - mu * mu, 0.0f);
  float rstd = rsqrtf(var + 1e-12f);
  float4 g1 = ((const float4*)g)[t];
  float4 b1v = ((const float4*)bta)[t];
  float4 g2 = ((const float4*)g)[256 + t];
  float4 b2v = ((const float4*)bta)[256 + t];
  float4 o1, o2;
  o1.x = (a.x - mu)*rstd*g1.x + b1v.x;  o1.y = (a.y - mu)*rstd*g1.y + b1v.y;
  o1.z = (a.z - mu)*rstd*g1.z + b1v.z;  o1.w = (a.w - mu)*rstd*g1.w + b1v.w;
  o2.x = (b.x - mu)*rstd*g2.x + b2v.x;  o2.y = (b.y - mu)*rstd*g2.y + b2v.y;
  o2.z = (b.z - mu)*rstd*g2.z + b2v.z;  o2.w = (b.w - mu)*rstd*g2.w + b2v.w;
  float4* orow = (float4*)(out + (size_t)row * (2*DD));
  orow[t] = o1;
  orow[256 + t] = o2;
}

// ---------------------------------------------------------------------------
// weight convert fp32 W[K][·] (row stride ldw) cols [0,N) -> bf16 splits
// Wt[NSPLIT][Npad][K] (zero pad n>=N)
template<int NSPLIT>
__global__ __launch_bounds__(256) void wconv_kernel(const float* __restrict__ W,
                                                    unsigned short* __restrict__ Wt,
                                                    int K, int N, int Npad, int ldw) {
  __shared__ float tile[32][33];
  int n0 = blockIdx.x * 32, k0 = blockIdx.y * 32;
  int tid = threadIdx.x;
  #pragma unroll
  for (int i = 0; i < 4; i++) {
    int idx = i*256 + tid;
    int kk = idx >> 5, nn = idx & 31;
    float v = 0.0f;
    if (n0 + nn < N) v = W[(size_t)(k0 + kk) * ldw + n0 + nn];
    tile[kk][nn] = v;
  }
  __syncthreads();
  size_t NKs = (size_t)Npad * K;
  #pragma unroll
  for (int i = 0; i < 4; i++) {
    int idx = i*256 + tid;
    int nn = idx >> 5, kk = idx & 31;
    float v = tile[kk][nn];
    size_t off = (size_t)(n0 + nn) * K + k0 + kk;
    float c = v;
    #pragma unroll
    for (int p = 0; p < NSPLIT; p++) {
      unsigned short hh = f2bf(c);
      Wt[(size_t)p * NKs + off] = hh;
      c -= bf2f(hh);
    }
  }
}

// ---------------------------------------------------------------------------
// MFMA GEMM with fp32 A, in-register bf16 split.
// SIX=true: 6-term bf16x3 (fp32-equivalent); SIX=false: 1-term plain bf16.
// A fp32 [M][K]; Bt bf16 [SIX?3:1][N][K] (plane stride bplane); C fp32 [M][N].
// CMODE: 0 = store, 1 = accumulate.
template<bool SIX, int CMODE, bool BIAS, bool RELU>
__global__ __launch_bounds__(256) void mgemmf_kernel(const float* __restrict__ A,
                                                     const unsigned short* __restrict__ Bt,
                                                     const float* __restrict__ bias,
                                                     float* __restrict__ C,
                                                     int M, int N, int K, size_t bplane) {
  __shared__ __align__(16) float Af[128*32];               // 16 KB, XOR-swizzled 16B slots
  __shared__ __align__(16) unsigned short Bs[3*128*32];    // 24 KB (plane 0 only if !SIX)
  int tid = threadIdx.x, lane = tid & 63, wave = tid >> 6;
  int m0 = blockIdx.y * 128, n0 = blockIdx.x * 128;
  int wm = (wave & 1) * 64, wn = (wave >> 1) * 64;
  int lm = lane & 15, quad = lane >> 4;
  const int NCH = SIX ? 10 : 6;                            // chunks/wave (total 40 / 24)
  v4f acc[4][4];
  #pragma unroll
  for (int i = 0; i < 4; i++)
    #pragma unroll
    for (int j = 0; j < 4; j++) acc[i][j] = (v4f)0.0f;

  for (int k0 = 0; k0 < K; k0 += 32) {
    #pragma unroll
    for (int i = 0; i < NCH; i++) {
      int c = wave * NCH + i;
      if (c < 16) {
        // A chunk: 1 KB = 64 16B-slots; slot = row*8 + j, holds col4 = j^(row&7)
        int slot = c * 64 + lane;
        int row = slot >> 3;
        int c4 = (slot & 7) ^ (row & 7);
        gld16(A + (size_t)(m0 + row) * K + k0 + c4 * 4, (char*)Af + (size_t)c * 1024);
      } else {
        int cb = c - 16;
        int p = cb >> 3, q = cb & 7;                       // plane, chunk-in-plane
        int eo = q * 512 + lane * 8;
        int row = eo >> 5, col = eo & 31;
        gld16(Bt + (size_t)p * bplane + (size_t)(n0 + row) * K + k0 + col,
              (char*)Bs + (size_t)p * 8192 + (size_t)q * 1024);
      }
    }
    __syncthreads();
    v8s b0[4], b1[4], b2[4];
    #pragma unroll
    for (int ni = 0; ni < 4; ni++) {
      int boff = (wn + ni*16 + lm) * 32 + quad * 8;
      b0[ni] = *(const v8s*)&Bs[boff];
      if (SIX) {
        b1[ni] = *(const v8s*)&Bs[4096 + boff];
        b2[ni] = *(const v8s*)&Bs[8192 + boff];
      }
    }
    #pragma unroll
    for (int mi = 0; mi < 4; mi++) {
      int arow = wm + mi*16 + lm;
      int sw = arow & 7;
      float4 fA = *(const float4*)(Af + arow*32 + (((2*quad)     ^ sw) << 2));
      float4 fB = *(const float4*)(Af + arow*32 + (((2*quad + 1) ^ sw) << 2));
      union { v8s v; unsigned int u[4]; } a0, a1, a2;
      a0.u[0] = pack_bf2(fA.x, fA.y);
      a0.u[1] = pack_bf2(fA.z, fA.w);
      a0.u[2] = pack_bf2(fB.x, fB.y);
      a0.u[3] = pack_bf2(fB.z, fB.w);
      if (SIX) {
        float r0 = fA.x - lo_f(a0.u[0]), r1 = fA.y - hi_f(a0.u[0]);
        float r2 = fA.z - lo_f(a0.u[1]), r3 = fA.w - hi_f(a0.u[1]);
        float r4 = fB.x - lo_f(a0.u[2]), r5 = fB.y - hi_f(a0.u[2]);
        float r6 = fB.z - lo_f(a0.u[3]), r7 = fB.w - hi_f(a0.u[3]);
        a1.u[0] = pack_bf2(r0, r1); a1.u[1] = pack_bf2(r2, r3);
        a1.u[2] = pack_bf2(r4, r5); a1.u[3] = pack_bf2(r6, r7);
        float t0 = r0 - lo_f(a1.u[0]), t1 = r1 - hi_f(a1.u[0]);
        float t2 = r2 - lo_f(a1.u[1]), t3 = r3 - hi_f(a1.u[1]);
        float t4 = r4 - lo_f(a1.u[2]), t5 = r5 - hi_f(a1.u[2]);
        float t6 = r6 - lo_f(a1.u[3]), t7 = r7 - hi_f(a1.u[3]);
        a2.u[0] = pack_bf2(t0, t1); a2.u[1] = pack_bf2(t2, t3);
        a2.u[2] = pack_bf2(t4, t5); a2.u[3] = pack_bf2(t6, t7);
      }
      #pragma unroll
      for (int ni = 0; ni < 4; ni++) {
        v4f c0 = acc[mi][ni];
        c0 = __builtin_amdgcn_mfma_f32_16x16x32_bf16(a0.v, b0[ni], c0, 0, 0, 0);
        if (SIX) {
          c0 = __builtin_amdgcn_mfma_f32_16x16x32_bf16(a0.v, b1[ni], c0, 0, 0, 0);
          c0 = __builtin_amdgcn_mfma_f32_16x16x32_bf16(a1.v, b0[ni], c0, 0, 0, 0);
          c0 = __builtin_amdgcn_mfma_f32_16x16x32_bf16(a1.v, b1[ni], c0, 0, 0, 0);
          c0 = __builtin_amdgcn_mfma_f32_16x16x32_bf16(a0.v, b2[ni], c0, 0, 0, 0);
          c0 = __builtin_amdgcn_mfma_f32_16x16x32_bf16(a2.v, b0[ni], c0, 0, 0, 0);
        }
        acc[mi][ni] = c0;
      }
    }
    __syncthreads();
  }

  #pragma unroll
  for (int mi = 0; mi < 4; mi++) {
    int rbase = m0 + wm + mi*16 + quad*4;
    #pragma unroll
    for (int ni = 0; ni < 4; ni++) {
      int col = n0 + wn + ni*16 + lm;
      float bv = BIAS ? bias[col] : 0.0f;
      #pragma unroll
      for (int r = 0; r < 4; r++) {
        float val = acc[mi][ni][r] + bv;
        if (RELU) val = fmaxf(val, 0.0f);
        size_t off = (size_t)(rbase + r) * N + col;
        if (CMODE == 1) C[off] += val; else C[off] = val;
      }
    }
  }
}

// ---------------------------------------------------------------------------
// buckets: one wave per (b,h,s); fp64 accumulation for argmax stability
__global__ __launch_bounds__(64) void bucket_kernel(const float* __restrict__ qk,
                                                    const float* __restrict__ rot,
                                                    int* __restrict__ ids) {
  int blk = blockIdx.x;
  int s = blk & (SS - 1);
  int bh = blk >> 12;
  int b = bh >> 3, h = bh & 7;
  int lane = threadIdx.x;
  __shared__ float qv[DH];
  const float* qrow = qk + ((size_t)(b * SS + s)) * DD + h * DH;
  qv[lane] = qrow[lane];
  qv[lane + 64] = qrow[lane + 64];
  __syncthreads();
  const float* rh = rot + (size_t)h * (DH * RR * 64);
  for (int r = 0; r < RR; r++) {
    const float* rp = rh + r * 64 + lane;
    double acc = 0.0;
    #pragma unroll 4
    for (int d = 0; d < DH; d++) acc += (double)qv[d] * (double)rp[(size_t)d * 128];
    double bvv; int bi;
    if (acc >= -acc) { bvv = acc; bi = lane; } else { bvv = -acc; bi = 64 + lane; }
    #pragma unroll
    for (int o = 1; o < 64; o <<= 1) {
      double ov = __shfl_xor(bvv, o);
      int oi = __shfl_xor(bi, o);
      if (ov > bvv || (ov == bvv && oi < bi)) { bvv = ov; bi = oi; }
    }
    if (lane == 0) ids[((size_t)bh * RR + r) * SS + s] = bi + r * NBUCK;
  }
}

// ---------------------------------------------------------------------------
__global__ __launch_bounds__(256) void sort_kernel(const int* __restrict__ ids,
                                                   int* __restrict__ orig,
                                                   int* __restrict__ undo) {
  int bh = blockIdx.x;
  int t = threadIdx.x;
  int r = t >> 7;
  const int* idp = ids + ((size_t)bh * RR + r) * SS;
  __shared__ int offs[256];
  int c = 0;
  for (int s = 0; s < SS; s++) c += (idp[s] == t) ? 1 : 0;
  offs[t] = c;
  __syncthreads();
  if (t == 0) {
    int acc = 0;
    for (int i = 0; i < 256; i++) { int cc = offs[i]; offs[i] = acc; acc += cc; }
  }
  __syncthreads();
  int o = offs[t];
  for (int s = 0; s < SS; s++) {
    if (idp[s] == t) {
      orig[(size_t)bh * RS + o] = s;
      undo[(size_t)bh * RS + r * SS + s] = o;
      o++;
    }
  }
}

// ---------------------------------------------------------------------------
__global__ __launch_bounds__(256) void rnorm_kernel(const float* __restrict__ qk,
                                                    const int* __restrict__ orig,
                                                    float* __restrict__ rno) {
  int idx = blockIdx.x * 4 + (threadIdx.x >> 6);
  int lane = threadIdx.x & 63;
  int bh = idx >> 13;
  int k = idx & (RS - 1);
  int b = bh >> 3, h = bh & 7;
  int s = orig[(size_t)bh * RS + k];
  const float* row = qk + ((size_t)(b * SS + s)) * DD + h * DH;
  float x0 = row[lane], x1 = row[lane + 64];
  float ss = x0 * x0 + x1 * x1;
  #pragma unroll
  for (int o = 1; o < 64; o <<= 1) ss += __shfl_xor(ss, o);
  if (lane == 0)
    rno[(size_t)bh * RS + k] = rsqrtf(ss * (1.0f / DH) + 1e-6f) * 0.08838834764831845f;
}

// ---------------------------------------------------------------------------
// chunked attention, all fp32 (R1-verified)
__global__ __launch_bounds__(256) void attn_kernel(const float* __restrict__ qk,
                                                   const float* __restrict__ v,
                                                   const int* __restrict__ orig,
                                                   const float* __restrict__ rno,
                                                   float* __restrict__ osort,
                                                   float* __restrict__ lg) {
  __shared__ float qs[64 * 128];
  __shared__ float kb[128 * 64];
  int blk = blockIdx.x;
  int n = blk & (NC - 1);
  int bh = blk >> 7;
  int b = bh >> 3, h = bh & 7;
  int pn = (n + NC - 1) & (NC - 1);
  int tid = threadIdx.x;
  int wave = tid >> 6, lane = tid & 63;
  const int* origp = orig + (size_t)bh * RS;
  const float* rnp = rno + (size_t)bh * RS;
  const size_t base = (size_t)b * SS * DD + (size_t)h * DH;

  for (int idx = tid; idx < 64 * 128; idx += 256) {
    int c = idx >> 7, d = idx & 127;
    qs[idx] = qk[base + (size_t)origp[n * 64 + c] * DD + d];
  }
  for (int idx = tid; idx < 64 * 128; idx += 256) {
    int j = idx >> 7, d = idx & 127;
    int kidx = pn * 64 + j;
    kb[d * 64 + (j ^ (d & 63))] = qk[base + (size_t)origp[kidx] * DD + d] * rnp[kidx];
  }
  int kpA = origp[pn * 64 + lane];
  int kpB = origp[n * 64 + lane];
  int qp_reg = origp[n * 64 + wave * 16 + (lane & 15)];
  float accA[16], accB[16];
  #pragma unroll
  for (int c = 0; c < 16; c++) { accA[c] = 0.f; accB[c] = 0.f; }
  __syncthreads();

  const float* qw = qs + wave * (16 * 128);
  #pragma unroll 2
  for (int d = 0; d < 128; d++) {
    float kv0 = kb[d * 64 + (lane ^ (d & 63))];
    #pragma unroll
    for (int c = 0; c < 16; c++) accA[c] += qw[c * 128 + d] * kv0;
  }
  __syncthreads();
  for (int idx = tid; idx < 64 * 128; idx += 256) {
    int j = idx >> 7, d = idx & 127;
    int kidx = n * 64 + j;
    kb[d * 64 + (j ^ (d & 63))] = qk[base + (size_t)origp[kidx] * DD + d] * rnp[kidx];
  }
  __syncthreads();
  #pragma unroll 2
  for (int d = 0; d < 128; d++) {
    float kv0 = kb[d * 64 + (lane ^ (d & 63))];
    #pragma unroll
    for (int c = 0; c < 16; c++) accB[c] += qw[c * 128 + d] * kv0;
  }

  float pA[16], pB[16];
  #pragma unroll
  for (int ci = 0; ci < 16; ci++) {
    int qp = __shfl(qp_reg, ci);
    float sA = (kpA > qp) ? -1000000000.0f : ((kpA == qp) ? -100000.0f : accA[ci]);
    float sB = (kpB > qp) ? -1000000000.0f : ((kpB == qp) ? -100000.0f : accB[ci]);
    float m = fmaxf(sA, sB);
    #pragma unroll
    for (int o = 1; o < 64; o <<= 1) m = fmaxf(m, __shfl_xor(m, o));
    float eA = __expf(sA - m), eB = __expf(sB - m);
    float sum = eA + eB;
    #pragma unroll
    for (int o = 1; o < 64; o <<= 1) sum += __shfl_xor(sum, o);
    pA[ci] = eA / sum;
    pB[ci] = eB / sum;
    if (lane == 0) lg[(size_t)bh * RS + n * 64 + wave * 16 + ci] = m + __logf(sum);
  }
  __syncthreads();

  #pragma unroll
  for (int ci = 0; ci < 16; ci++) {
    qs[(wave * 16 + ci) * 128 + lane] = pA[ci];
    qs[(wave * 16 + ci) * 128 + 64 + lane] = pB[ci];
  }
  for (int idx = tid; idx < 64 * 128; idx += 256) {
    int j = idx >> 7, d = idx & 127;
    kb[j * 128 + d] = v[base + (size_t)origp[pn * 64 + j] * DD + d];
  }
  __syncthreads();
  float o0[16], o1[16];
  #pragma unroll
  for (int c = 0; c < 16; c++) { o0[c] = 0.f; o1[c] = 0.f; }
  #pragma unroll 2
  for (int j = 0; j < 64; j++) {
    float v0 = kb[j * 128 + lane];
    float v1 = kb[j * 128 + 64 + lane];
    #pragma unroll
    for (int c = 0; c < 16; c++) {
      float p = qw[c * 128 + j];
      o0[c] += p * v0; o1[c] += p * v1;
    }
  }
  __syncthreads();
  for (int idx = tid; idx < 64 * 128; idx += 256) {
    int j = idx >> 7, d = idx & 127;
    kb[j * 128 + d] = v[base + (size_t)origp[n * 64 + j] * DD + d];
  }
  __syncthreads();
  #pragma unroll 2
  for (int j = 0; j < 64; j++) {
    float v0 = kb[j * 128 + lane];
    float v1 = kb[j * 128 + 64 + lane];
    #pragma unroll
    for (int c = 0; c < 16; c++) {
      float p = qw[c * 128 + 64 + j];
      o0[c] += p * v0; o1[c] += p * v1;
    }
  }
  #pragma unroll
  for (int ci = 0; ci < 16; ci++) {
    size_t off = ((size_t)bh * RS + n * 64 + wave * 16 + ci) * DH;
    osort[off + lane] = o0[ci];
    osort[off + 64 + lane] = o1[ci];
  }
}

// ---------------------------------------------------------------------------
__global__ __launch_bounds__(256) void unsort_kernel(const float* __restrict__ osort,
                                                     const float* __restrict__ lg,
                                                     const int* __restrict__ undo,
                                                     float* __restrict__ attn) {
  int gid = blockIdx.x * 4 + (threadIdx.x >> 6);
  int lane = threadIdx.x & 63;
  int bh = gid >> 12;
  int s = gid & (SS - 1);
  int b = bh >> 3, h = bh & 7;
  int k0 = undo[(size_t)bh * RS + s];
  int k1 = undo[(size_t)bh * RS + SS + s];
  float l0 = lg[(size_t)bh * RS + k0], l1 = lg[(size_t)bh * RS + k1];
  float m = fmaxf(l0, l1);
  float e0 = __expf(l0 - m), e1 = __expf(l1 - m);
  float inv = 1.0f / (e0 + e1);
  float w0 = e0 * inv, w1 = e1 * inv;
  const float* r0 = osort + ((size_t)bh * RS + k0) * DH;
  const float* r1 = osort + ((size_t)bh * RS + k1) * DH;
  float* outp = attn + ((size_t)(b * SS + s)) * DD + h * DH;
  outp[lane]      = w0 * r0[lane]      + w1 * r1[lane];
  outp[lane + 64] = w0 * r0[lane + 64] + w1 * r1[lane + 64];
}

// ---------------------------------------------------------------------------
__global__ __launch_bounds__(256) void softmax_b_kernel(const float* __restrict__ logits,
                                                        const float* __restrict__ bout,
                                                        float* __restrict__ out) {
  int i = blockIdx.x * 256 + threadIdx.x;
  if (i >= SS * VV) return;
  int s = i / VV, vv = i - s * VV;
  float bvv = bout[vv];
  float l0 = logits[(size_t)s * VP + vv] + bvv;
  float l1 = logits[(size_t)(SS + s) * VP + vv] + bvv;
  float m = fmaxf(l0, l1);
  float e0 = __expf(l0 - m), e1 = __expf(l1 - m);
  float inv = 1.0f / (e0 + e1);
  out[(size_t)s * VV + vv] = e0 * inv;
  out[(size_t)(SS + s) * VV + vv] = e1 * inv;
}

// ---------------------------------------------------------------------------
// Workspace layout — total extent 237,502,464 B (== R1's proven footprint):
//   x1, x2, h: 3*NX f32
//   pool: 4*NX f32
//     attn phase: qkb=pool[0,NX) vb=[NX,2NX) osort=[2NX,4NX)
//     FFN  phase: ff=[0,2NX) ([8192][2048] f32, K-half), weights squat [2NX,..)
//     head phase: hcat=[0,2NX), wout squat [2NX,..)
//   weights (bf16 planes) live ONLY in pool[2NX..) when osort is dead:
//     wqk_t/wv_t (3 planes, 6.3 MB) before attn writes osort; wo_t after unsort;
//     FFN half planes (12.6 MB) and wout after attention retires.
//   misc (lgb/rno/orig/undo/ids): 2.6 MB after pool.
extern "C" void kernel_launch(void* const* d_in, const int* in_sizes, int n_in,
                              void* d_out, int out_size, void* d_ws, size_t ws_size,
                              hipStream_t stream) {
  (void)in_sizes; (void)n_in; (void)out_size; (void)ws_size;
  const float* x     = (const float*)d_in[0];
  const float* ln1_g = (const float*)d_in[1];
  const float* ln1_b = (const float*)d_in[2];
  const float* Wqk   = (const float*)d_in[3];
  const float* Wv    = (const float*)d_in[4];
  const float* Wo    = (const float*)d_in[5];
  const float* rot   = (const float*)d_in[6];
  const float* ln2_g = (const float*)d_in[7];
  const float* ln2_b = (const float*)d_in[8];
  const float* W1    = (const float*)d_in[9];
  const float* b1    = (const float*)d_in[10];
  const float* W2    = (const float*)d_in[11];
  const float* b2    = (const float*)d_in[12];
  const float* lnf_g = (const float*)d_in[13];
  const float* lnf_b = (const float*)d_in[14];
  const float* Wout  = (const float*)d_in[15];
  const float* bout  = (const float*)d_in[16];

  const size_t NX = (size_t)MROWS * DD;            // 8,388,608
  float* x1 = (float*)d_ws;
  float* x2 = x1 + NX;
  float* h  = x2 + NX;
  float* pool = h + NX;                            // 4*NX floats
  float* qkb   = pool;
  float* vb    = pool + NX;
  float* osort = pool + 2*NX;
  float* ff    = pool;                             // [8192][2048] f32, FFN K-half
  float* hcat  = pool;                             // [8192][2048] f32, head phase
  unsigned short* wt = (unsigned short*)(pool + 2*NX);   // weight squat region (<=67 MB)
  float* after = pool + 4*NX;
  float* lgb = after;
  float* rno = lgb + (size_t)BH * RS;
  int* orig = (int*)(rno + (size_t)BH * RS);
  int* undo = orig + (size_t)BH * RS;
  int* ids  = undo + (size_t)BH * RS;
  float* logitsP = h;                              // [8192][VP] f32, head phase

  const size_t BP_D  = (size_t)DD * DD;            // 1,048,576 (qk/v/wo plane)
  const size_t BP_FF = (size_t)2048 * DD * 2;      // NO — see per-call values below

  init_x_kernel<<<(int)(NX / 256), 256, 0, stream>>>(x, x1, x2);

  for (int l = 0; l < LL; l++) {
    // --- attention ---
    ln_kernel<<<MROWS, 256, 0, stream>>>(x2, ln1_g + l*DD, ln1_b + l*DD, h);

    // qk (bucket-critical, always 6-term). wt squats where osort will later live.
    wconv_kernel<3><<<dim3(32, 32), 256, 0, stream>>>(Wqk + (size_t)l*DD*DD, wt, DD, DD, DD, DD);
    mgemmf_kernel<true,0,false,false><<<dim3(8, 64), 256, 0, stream>>>(
        h, wt, nullptr, qkb, MROWS, DD, DD, BP_D);

    // v: layer 0 bucket-critical (feeds residual -> layer1 buckets), layer 1 relaxed
    if (l == 0) {
      wconv_kernel<3><<<dim3(32, 32), 256, 0, stream>>>(Wv + (size_t)l*DD*DD, wt, DD, DD, DD, DD);
      mgemmf_kernel<true,0,false,false><<<dim3(8, 64), 256, 0, stream>>>(
          h, wt, nullptr, vb, MROWS, DD, DD, BP_D);
    } else {
      wconv_kernel<1><<<dim3(32, 32), 256, 0, stream>>>(Wv + (size_t)l*DD*DD, wt, DD, DD, DD, DD);
      mgemmf_kernel<false,0,false,false><<<dim3(8, 64), 256, 0, stream>>>(
          h, wt, nullptr, vb, MROWS, DD, DD, BP_D);
    }

    bucket_kernel<<<BB*HH*SS, 64, 0, stream>>>(qkb, rot + (size_t)l*HH*DH*RR*64, ids);
    sort_kernel<<<BH, 256, 0, stream>>>(ids, orig, undo);
    rnorm_kernel<<<BH*RS/4, 256, 0, stream>>>(qkb, orig, rno);
    attn_kernel<<<BH*NC, 256, 0, stream>>>(qkb, vb, orig, rno, osort, lgb);   // writes osort
    unsort_kernel<<<BH*SS/4, 256, 0, stream>>>(osort, lgb, undo, h);          // osort dead after

    // Wo (wt overwrites dead osort)
    if (l == 0) {
      wconv_kernel<3><<<dim3(32, 32), 256, 0, stream>>>(Wo + (size_t)l*DD*DD, wt, DD, DD, DD, DD);
      mgemmf_kernel<true,1,false,false><<<dim3(8, 64), 256, 0, stream>>>(
          h, wt, nullptr, x1, MROWS, DD, DD, BP_D);
    } else {
      wconv_kernel<1><<<dim3(32, 32), 256, 0, stream>>>(Wo + (size_t)l*DD*DD, wt, DD, DD, DD, DD);
      mgemmf_kernel<false,1,false,false><<<dim3(8, 64), 256, 0, stream>>>(
          h, wt, nullptr, x1, MROWS, DD, DD, BP_D);
    }

    // --- FFN, split into two FF-halves of 2048 so ff fits in pool[0,2NX) ---
    ln_kernel<<<MROWS, 256, 0, stream>>>(x1, ln2_g + l*DD, ln2_b + l*DD, h);
    for (int hf = 0; hf < 2; hf++) {
      const float* W1h = W1 + (size_t)l*DD*FFD + (size_t)hf*2048;     // [1024][·] cols half
      const float* W2h = W2 + (size_t)l*FFD*DD + (size_t)hf*2048*DD;  // rows half, [2048][1024]
      unsigned short* wt1 = wt;                       // [3][2048][1024] = 12.6 MB
      unsigned short* wt2 = wt + 3u*2097152u;         // [3][1024][2048] = 12.6 MB
      if (l == 0) {
        wconv_kernel<3><<<dim3(64, 32), 256, 0, stream>>>(W1h, wt1, DD, 2048, 2048, FFD);
        mgemmf_kernel<true,0,true,true><<<dim3(16, 64), 256, 0, stream>>>(
            h, wt1, b1 + (size_t)l*FFD + hf*2048, ff, MROWS, 2048, DD, 2097152u);
        wconv_kernel<3><<<dim3(32, 64), 256, 0, stream>>>(W2h, wt2, 2048, DD, DD, DD);
        if (hf == 0)
          mgemmf_kernel<true,1,true,false><<<dim3(8, 64), 256, 0, stream>>>(
              ff, wt2, b2 + (size_t)l*DD, x2, MROWS, DD, 2048, 2097152u);
        else
          mgemmf_kernel<true,1,false,false><<<dim3(8, 64), 256, 0, stream>>>(
              ff, wt2, nullptr, x2, MROWS, DD, 2048, 2097152u);
      } else {
        wconv_kernel<1><<<dim3(64, 32), 256, 0, stream>>>(W1h, wt1, DD, 2048, 2048, FFD);
        mgemmf_kernel<false,0,true,true><<<dim3(16, 64), 256, 0, stream>>>(
            h, wt1, b1 + (size_t)l*FFD + hf*2048, ff, MROWS, 2048, DD, 2097152u);
        wconv_kernel<1><<<dim3(32, 64), 256, 0, stream>>>(W2h, wt2, 2048, DD, DD, DD);
        if (hf == 0)
          mgemmf_kernel<false,1,true,false><<<dim3(8, 64), 256, 0, stream>>>(
              ff, wt2, b2 + (size_t)l*DD, x2, MROWS, DD, 2048, 2097152u);
        else
          mgemmf_kernel<false,1,false,false><<<dim3(8, 64), 256, 0, stream>>>(
              ff, wt2, nullptr, x2, MROWS, DD, 2048, 2097152u);
      }
    }
  }

  // --- head ---
  ln_concat_kernel<<<MROWS, 256, 0, stream>>>(x1, x2, lnf_g, lnf_b, hcat);
  wconv_kernel<1><<<dim3(12, 64), 256, 0, stream>>>(Wout, wt, 2*DD, VV, VP, VV);
  mgemmf_kernel<false,0,false,false><<<dim3(3, 64), 256, 0, stream>>>(
      hcat, wt, nullptr, logitsP, MROWS, VP, 2*DD, 0u);
  softmax_b_kernel<<<(SS*VV + 255)/256, 256, 0, stream>>>(logitsP, bout, (float*)d_out);
  (void)BP_FF;
}

// Round 5
// 3138.470 us; speedup vs baseline: 2.7095x; 1.3374x over previous
//
#include <hip/hip_runtime.h>
#include <hip/hip_bf16.h>
#include <math.h>

#define BB 2
#define SS 4096
#define DD 1024
#define HH 8
#define DH 128
#define RR 2
#define CC 64
#define NBUCK 128
#define LL 2
#define FFD 4096
#define VV 258
#define VP 384            // padded vocab for head GEMM (multiple of 128)
#define RS (RR*SS)        // 8192
#define NC (RS/CC)        // 128
#define BH (BB*HH)        // 16
#define MROWS (BB*SS)     // 8192

typedef __attribute__((ext_vector_type(8))) short v8s;
typedef __attribute__((ext_vector_type(4))) float v4f;

// ---------------------------------------------------------------------------
__device__ __forceinline__ unsigned short f2bf(float f) {
  unsigned int u = __float_as_uint(f);
  u = (u + 0x7FFFu + ((u >> 16) & 1u)) >> 16;     // round-to-nearest-even
  return (unsigned short)u;
}
__device__ __forceinline__ float bf2f(unsigned short h) {
  return __uint_as_float(((unsigned int)h) << 16);
}
__device__ __forceinline__ unsigned int pack_bf2(float a, float b) {
  __hip_bfloat162 h = __float22bfloat162_rn(make_float2(a, b));
  union { __hip_bfloat162 h2; unsigned int u; } cv;
  cv.h2 = h;
  return cv.u;
}
__device__ __forceinline__ float lo_f(unsigned int u) { return __uint_as_float(u << 16); }
__device__ __forceinline__ float hi_f(unsigned int u) { return __uint_as_float(u & 0xFFFF0000u); }

__device__ __forceinline__ void gld16(const void* g, void* l) {
  __builtin_amdgcn_global_load_lds((const __attribute__((address_space(1))) void*)g,
                                   (__attribute__((address_space(3))) void*)l, 16, 0, 0);
}

// ---------------------------------------------------------------------------
__device__ __forceinline__ void block_sum2(float& s, float& s2) {
  #pragma unroll
  for (int o = 1; o < 64; o <<= 1) { s += __shfl_xor(s, o); s2 += __shfl_xor(s2, o); }
  __shared__ float rs[4], rq[4];
  int wave = threadIdx.x >> 6;
  if ((threadIdx.x & 63) == 0) { rs[wave] = s; rq[wave] = s2; }
  __syncthreads();
  s  = rs[0] + rs[1] + rs[2] + rs[3];
  s2 = rq[0] + rq[1] + rq[2] + rq[3];
}

// ---------------------------------------------------------------------------
__global__ __launch_bounds__(256) void init_x_kernel(const float* __restrict__ x,
                                                     float* __restrict__ x1,
                                                     float* __restrict__ x2) {
  size_t i = (size_t)blockIdx.x * 256 + threadIdx.x;
  float v = x[i];
  x1[i] = v; x2[i] = v;
}

// ---------------------------------------------------------------------------
// LayerNorm over D=1024, fp32 out
__global__ __launch_bounds__(256) void ln_kernel(const float* __restrict__ x,
                                                 const float* __restrict__ g,
                                                 const float* __restrict__ bta,
                                                 float* __restrict__ out) {
  int row = blockIdx.x;
  int t = threadIdx.x;
  float4 xv = ((const float4*)(x + (size_t)row * DD))[t];
  float s  = xv.x + xv.y + xv.z + xv.w;
  float s2 = xv.x*xv.x + xv.y*xv.y + xv.z*xv.z + xv.w*xv.w;
  block_sum2(s, s2);
  float mu   = s * (1.0f / DD);
  float var  = fmaxf(s2 * (1.0f / DD) - mu * mu, 0.0f);
  float rstd = rsqrtf(var + 1e-12f);
  float4 gv = ((const float4*)g)[t];
  float4 bv = ((const float4*)bta)[t];
  float4 ov;
  ov.x = (xv.x - mu) * rstd * gv.x + bv.x;
  ov.y = (xv.y - mu) * rstd * gv.y + bv.y;
  ov.z = (xv.z - mu) * rstd * gv.z + bv.z;
  ov.w = (xv.w - mu) * rstd * gv.w + bv.w;
  ((float4*)(out + (size_t)row * DD))[t] = ov;
}

// LayerNorm over concat([x1,x2]) (2048), fp32 out
__global__ __launch_bounds__(256) void ln_concat_kernel(const float* __restrict__ x1,
                                                        const float* __restrict__ x2,
                                                        const float* __restrict__ g,
                                                        const float* __restrict__ bta,
                                                        float* __restrict__ out) {
  int row = blockIdx.x;
  int t = threadIdx.x;
  float4 a = ((const float4*)(x1 + (size_t)row * DD))[t];
  float4 b = ((const float4*)(x2 + (size_t)row * DD))[t];
  float s  = a.x + a.y + a.z + a.w + b.x + b.y + b.z + b.w;
  float s2 = a.x*a.x + a.y*a.y + a.z*a.z + a.w*a.w
           + b.x*b.x + b.y*b.y + b.z*b.z + b.w*b.w;
  block_sum2(s, s2);
  float mu   = s * (1.0f / (2*DD));
  float var  = fmaxf(s2 * (1.0f / (2*DD)) - mu * mu, 0.0f);
  float rstd = rsqrtf(var + 1e-12f);
  float4 g1 = ((const float4*)g)[t];
  float4 b1v = ((const float4*)bta)[t];
  float4 g2 = ((const float4*)g)[256 + t];
  float4 b2v = ((const float4*)bta)[256 + t];
  float4 o1, o2;
  o1.x = (a.x - mu)*rstd*g1.x + b1v.x;  o1.y = (a.y - mu)*rstd*g1.y + b1v.y;
  o1.z = (a.z - mu)*rstd*g1.z + b1v.z;  o1.w = (a.w - mu)*rstd*g1.w + b1v.w;
  o2.x = (b.x - mu)*rstd*g2.x + b2v.x;  o2.y = (b.y - mu)*rstd*g2.y + b2v.y;
  o2.z = (b.z - mu)*rstd*g2.z + b2v.z;  o2.w = (b.w - mu)*rstd*g2.w + b2v.w;
  float4* orow = (float4*)(out + (size_t)row * (2*DD));
  orow[t] = o1;
  orow[256 + t] = o2;
}

// ---------------------------------------------------------------------------
// weight convert fp32 W[K][·] (row stride ldw) cols [0,N) -> bf16 splits
// Wt[NSPLIT][Npad][K] (zero pad n>=N)
template<int NSPLIT>
__global__ __launch_bounds__(256) void wconv_kernel(const float* __restrict__ W,
                                                    unsigned short* __restrict__ Wt,
                                                    int K, int N, int Npad, int ldw) {
  __shared__ float tile[32][33];
  int n0 = blockIdx.x * 32, k0 = blockIdx.y * 32;
  int tid = threadIdx.x;
  #pragma unroll
  for (int i = 0; i < 4; i++) {
    int idx = i*256 + tid;
    int kk = idx >> 5, nn = idx & 31;
    float v = 0.0f;
    if (n0 + nn < N) v = W[(size_t)(k0 + kk) * ldw + n0 + nn];
    tile[kk][nn] = v;
  }
  __syncthreads();
  size_t NKs = (size_t)Npad * K;
  #pragma unroll
  for (int i = 0; i < 4; i++) {
    int idx = i*256 + tid;
    int nn = idx >> 5, kk = idx & 31;
    float v = tile[kk][nn];
    size_t off = (size_t)(n0 + nn) * K + k0 + kk;
    float c = v;
    #pragma unroll
    for (int p = 0; p < NSPLIT; p++) {
      unsigned short hh = f2bf(c);
      Wt[(size_t)p * NKs + off] = hh;
      c -= bf2f(hh);
    }
  }
}

// ---------------------------------------------------------------------------
// MFMA GEMM with fp32 A, in-register bf16 split.
// SIX=true: 6-term bf16x3 (fp32-equivalent); SIX=false: 1-term plain bf16.
// A fp32 [M][K]; Bt bf16 [SIX?3:1][N][K] (plane stride bplane); C fp32 [M][N].
// CMODE: 0 = store, 1 = accumulate.
template<bool SIX, int CMODE, bool BIAS, bool RELU>
__global__ __launch_bounds__(256) void mgemmf_kernel(const float* __restrict__ A,
                                                     const unsigned short* __restrict__ Bt,
                                                     const float* __restrict__ bias,
                                                     float* __restrict__ C,
                                                     int M, int N, int K, size_t bplane) {
  __shared__ __align__(16) float Af[128*32];               // 16 KB, XOR-swizzled 16B slots
  __shared__ __align__(16) unsigned short Bs[3*128*32];    // 24 KB (plane 0 only if !SIX)
  int tid = threadIdx.x, lane = tid & 63, wave = tid >> 6;
  int m0 = blockIdx.y * 128, n0 = blockIdx.x * 128;
  int wm = (wave & 1) * 64, wn = (wave >> 1) * 64;
  int lm = lane & 15, quad = lane >> 4;
  const int NCH = SIX ? 10 : 6;                            // chunks/wave (total 40 / 24)
  v4f acc[4][4];
  #pragma unroll
  for (int i = 0; i < 4; i++)
    #pragma unroll
    for (int j = 0; j < 4; j++) acc[i][j] = (v4f)0.0f;

  for (int k0 = 0; k0 < K; k0 += 32) {
    #pragma unroll
    for (int i = 0; i < NCH; i++) {
      int c = wave * NCH + i;
      if (c < 16) {
        // A chunk: 1 KB = 64 16B-slots; slot = row*8 + j, holds col4 = j^(row&7)
        int slot = c * 64 + lane;
        int row = slot >> 3;
        int c4 = (slot & 7) ^ (row & 7);
        gld16(A + (size_t)(m0 + row) * K + k0 + c4 * 4, (char*)Af + (size_t)c * 1024);
      } else {
        int cb = c - 16;
        int p = cb >> 3, q = cb & 7;                       // plane, chunk-in-plane
        int eo = q * 512 + lane * 8;
        int row = eo >> 5, col = eo & 31;
        gld16(Bt + (size_t)p * bplane + (size_t)(n0 + row) * K + k0 + col,
              (char*)Bs + (size_t)p * 8192 + (size_t)q * 1024);
      }
    }
    __syncthreads();
    v8s b0[4], b1[4], b2[4];
    #pragma unroll
    for (int ni = 0; ni < 4; ni++) {
      int boff = (wn + ni*16 + lm) * 32 + quad * 8;
      b0[ni] = *(const v8s*)&Bs[boff];
      if (SIX) {
        b1[ni] = *(const v8s*)&Bs[4096 + boff];
        b2[ni] = *(const v8s*)&Bs[8192 + boff];
      }
    }
    #pragma unroll
    for (int mi = 0; mi < 4; mi++) {
      int arow = wm + mi*16 + lm;
      int sw = arow & 7;
      float4 fA = *(const float4*)(Af + arow*32 + (((2*quad)     ^ sw) << 2));
      float4 fB = *(const float4*)(Af + arow*32 + (((2*quad + 1) ^ sw) << 2));
      union { v8s v; unsigned int u[4]; } a0, a1, a2;
      a0.u[0] = pack_bf2(fA.x, fA.y);
      a0.u[1] = pack_bf2(fA.z, fA.w);
      a0.u[2] = pack_bf2(fB.x, fB.y);
      a0.u[3] = pack_bf2(fB.z, fB.w);
      if (SIX) {
        float r0 = fA.x - lo_f(a0.u[0]), r1 = fA.y - hi_f(a0.u[0]);
        float r2 = fA.z - lo_f(a0.u[1]), r3 = fA.w - hi_f(a0.u[1]);
        float r4 = fB.x - lo_f(a0.u[2]), r5 = fB.y - hi_f(a0.u[2]);
        float r6 = fB.z - lo_f(a0.u[3]), r7 = fB.w - hi_f(a0.u[3]);
        a1.u[0] = pack_bf2(r0, r1); a1.u[1] = pack_bf2(r2, r3);
        a1.u[2] = pack_bf2(r4, r5); a1.u[3] = pack_bf2(r6, r7);
        float t0 = r0 - lo_f(a1.u[0]), t1 = r1 - hi_f(a1.u[0]);
        float t2 = r2 - lo_f(a1.u[1]), t3 = r3 - hi_f(a1.u[1]);
        float t4 = r4 - lo_f(a1.u[2]), t5 = r5 - hi_f(a1.u[2]);
        float t6 = r6 - lo_f(a1.u[3]), t7 = r7 - hi_f(a1.u[3]);
        a2.u[0] = pack_bf2(t0, t1); a2.u[1] = pack_bf2(t2, t3);
        a2.u[2] = pack_bf2(t4, t5); a2.u[3] = pack_bf2(t6, t7);
      }
      #pragma unroll
      for (int ni = 0; ni < 4; ni++) {
        v4f c0 = acc[mi][ni];
        c0 = __builtin_amdgcn_mfma_f32_16x16x32_bf16(a0.v, b0[ni], c0, 0, 0, 0);
        if (SIX) {
          c0 = __builtin_amdgcn_mfma_f32_16x16x32_bf16(a0.v, b1[ni], c0, 0, 0, 0);
          c0 = __builtin_amdgcn_mfma_f32_16x16x32_bf16(a1.v, b0[ni], c0, 0, 0, 0);
          c0 = __builtin_amdgcn_mfma_f32_16x16x32_bf16(a1.v, b1[ni], c0, 0, 0, 0);
          c0 = __builtin_amdgcn_mfma_f32_16x16x32_bf16(a0.v, b2[ni], c0, 0, 0, 0);
          c0 = __builtin_amdgcn_mfma_f32_16x16x32_bf16(a2.v, b0[ni], c0, 0, 0, 0);
        }
        acc[mi][ni] = c0;
      }
    }
    __syncthreads();
  }

  #pragma unroll
  for (int mi = 0; mi < 4; mi++) {
    int rbase = m0 + wm + mi*16 + quad*4;
    #pragma unroll
    for (int ni = 0; ni < 4; ni++) {
      int col = n0 + wn + ni*16 + lm;
      float bv = BIAS ? bias[col] : 0.0f;
      #pragma unroll
      for (int r = 0; r < 4; r++) {
        float val = acc[mi][ni][r] + bv;
        if (RELU) val = fmaxf(val, 0.0f);
        size_t off = (size_t)(rbase + r) * N + col;
        if (CMODE == 1) C[off] += val; else C[off] = val;
      }
    }
  }
}

// ---------------------------------------------------------------------------
// buckets: one wave per (b,h,s); fp64 accumulation for argmax stability
__global__ __launch_bounds__(64) void bucket_kernel(const float* __restrict__ qk,
                                                    const float* __restrict__ rot,
                                                    int* __restrict__ ids) {
  int blk = blockIdx.x;
  int s = blk & (SS - 1);
  int bh = blk >> 12;
  int b = bh >> 3, h = bh & 7;
  int lane = threadIdx.x;
  __shared__ float qv[DH];
  const float* qrow = qk + ((size_t)(b * SS + s)) * DD + h * DH;
  qv[lane] = qrow[lane];
  qv[lane + 64] = qrow[lane + 64];
  __syncthreads();
  const float* rh = rot + (size_t)h * (DH * RR * 64);
  for (int r = 0; r < RR; r++) {
    const float* rp = rh + r * 64 + lane;
    double acc = 0.0;
    #pragma unroll 4
    for (int d = 0; d < DH; d++) acc += (double)qv[d] * (double)rp[(size_t)d * 128];
    double bvv; int bi;
    if (acc >= -acc) { bvv = acc; bi = lane; } else { bvv = -acc; bi = 64 + lane; }
    #pragma unroll
    for (int o = 1; o < 64; o <<= 1) {
      double ov = __shfl_xor(bvv, o);
      int oi = __shfl_xor(bi, o);
      if (ov > bvv || (ov == bvv && oi < bi)) { bvv = ov; bi = oi; }
    }
    if (lane == 0) ids[((size_t)bh * RR + r) * SS + s] = bi + r * NBUCK;
  }
}

// ---------------------------------------------------------------------------
// Parallel stable counting sort, exact match to argsort(ids*S+pos).
// Keys for round r are in [r*128,(r+1)*128), so global order = r-major;
// within (bh,r): bin-major, then s ascending (stable).
// Phase 1: per-wave segment rank/count via 7-bit ballot equality masks.
__global__ __launch_bounds__(256) void sort_count_kernel(const int* __restrict__ ids,
                                                         int* __restrict__ counts) {
  int w = blockIdx.x * 4 + (threadIdx.x >> 6);   // wave id over [0, 32*64)
  int lane = threadIdx.x & 63;
  int bhr = w >> 6, seg = w & 63;
  int id = ids[(size_t)bhr * SS + seg * 64 + lane];
  int bin = id & 127;
  unsigned long long eq = ~0ull;
  #pragma unroll
  for (int bit = 0; bit < 7; bit++) {
    unsigned long long bal = __ballot((bin >> bit) & 1);
    eq &= ((bin >> bit) & 1) ? bal : ~bal;
  }
  int rank = __popcll(eq & ((1ull << lane) - 1ull));
  if (rank == 0)
    counts[((size_t)bhr * 64 + seg) * 128 + bin] = __popcll(eq);
}

// Phase 2: per (bh,r): bin totals over segs, exclusive scan over bins (+r*S),
// rewrite counts in place as absolute start offsets per (seg,bin).
__global__ __launch_bounds__(128) void sort_prefix_kernel(int* __restrict__ counts) {
  int bhr = blockIdx.x;
  int bin = threadIdx.x;                          // 0..127
  int r = bhr & 1;
  int* cp = counts + (size_t)bhr * 64 * 128;
  int total = 0;
  for (int seg = 0; seg < 64; seg++) total += cp[seg * 128 + bin];
  __shared__ int tot[128];
  tot[bin] = total;
  __syncthreads();
  for (int off = 1; off < 128; off <<= 1) {
    int t = (bin >= off) ? tot[bin - off] : 0;
    __syncthreads();
    tot[bin] += t;
    __syncthreads();
  }
  int run = tot[bin] - total + r * SS;            // exclusive prefix + round base
  for (int seg = 0; seg < 64; seg++) {
    int c = cp[seg * 128 + bin];
    cp[seg * 128 + bin] = run;
    run += c;
  }
}

// Phase 3: recompute rank, scatter orig/undo.
__global__ __launch_bounds__(256) void sort_scatter_kernel(const int* __restrict__ ids,
                                                           const int* __restrict__ offs,
                                                           int* __restrict__ orig,
                                                           int* __restrict__ undo) {
  int w = blockIdx.x * 4 + (threadIdx.x >> 6);
  int lane = threadIdx.x & 63;
  int bhr = w >> 6, seg = w & 63;
  int s = seg * 64 + lane;
  int id = ids[(size_t)bhr * SS + s];
  int bin = id & 127;
  unsigned long long eq = ~0ull;
  #pragma unroll
  for (int bit = 0; bit < 7; bit++) {
    unsigned long long bal = __ballot((bin >> bit) & 1);
    eq &= ((bin >> bit) & 1) ? bal : ~bal;
  }
  int rank = __popcll(eq & ((1ull << lane) - 1ull));
  int o = offs[((size_t)bhr * 64 + seg) * 128 + bin] + rank;
  int bh = bhr >> 1, r = bhr & 1;
  orig[(size_t)bh * RS + o] = s;
  undo[(size_t)bh * RS + r * SS + s] = o;
}

// ---------------------------------------------------------------------------
__global__ __launch_bounds__(256) void rnorm_kernel(const float* __restrict__ qk,
                                                    const int* __restrict__ orig,
                                                    float* __restrict__ rno) {
  int idx = blockIdx.x * 4 + (threadIdx.x >> 6);
  int lane = threadIdx.x & 63;
  int bh = idx >> 13;
  int k = idx & (RS - 1);
  int b = bh >> 3, h = bh & 7;
  int s = orig[(size_t)bh * RS + k];
  const float* row = qk + ((size_t)(b * SS + s)) * DD + h * DH;
  float x0 = row[lane], x1 = row[lane + 64];
  float ss = x0 * x0 + x1 * x1;
  #pragma unroll
  for (int o = 1; o < 64; o <<= 1) ss += __shfl_xor(ss, o);
  if (lane == 0)
    rno[(size_t)bh * RS + k] = rsqrtf(ss * (1.0f / DH) + 1e-6f) * 0.08838834764831845f;
}

// ---------------------------------------------------------------------------
// chunked attention, all fp32 (R1-verified)
__global__ __launch_bounds__(256) void attn_kernel(const float* __restrict__ qk,
                                                   const float* __restrict__ v,
                                                   const int* __restrict__ orig,
                                                   const float* __restrict__ rno,
                                                   float* __restrict__ osort,
                                                   float* __restrict__ lg) {
  __shared__ float qs[64 * 128];
  __shared__ float kb[128 * 64];
  int blk = blockIdx.x;
  int n = blk & (NC - 1);
  int bh = blk >> 7;
  int b = bh >> 3, h = bh & 7;
  int pn = (n + NC - 1) & (NC - 1);
  int tid = threadIdx.x;
  int wave = tid >> 6, lane = tid & 63;
  const int* origp = orig + (size_t)bh * RS;
  const float* rnp = rno + (size_t)bh * RS;
  const size_t base = (size_t)b * SS * DD + (size_t)h * DH;

  for (int idx = tid; idx < 64 * 128; idx += 256) {
    int c = idx >> 7, d = idx & 127;
    qs[idx] = qk[base + (size_t)origp[n * 64 + c] * DD + d];
  }
  for (int idx = tid; idx < 64 * 128; idx += 256) {
    int j = idx >> 7, d = idx & 127;
    int kidx = pn * 64 + j;
    kb[d * 64 + (j ^ (d & 63))] = qk[base + (size_t)origp[kidx] * DD + d] * rnp[kidx];
  }
  int kpA = origp[pn * 64 + lane];
  int kpB = origp[n * 64 + lane];
  int qp_reg = origp[n * 64 + wave * 16 + (lane & 15)];
  float accA[16], accB[16];
  #pragma unroll
  for (int c = 0; c < 16; c++) { accA[c] = 0.f; accB[c] = 0.f; }
  __syncthreads();

  const float* qw = qs + wave * (16 * 128);
  #pragma unroll 2
  for (int d = 0; d < 128; d++) {
    float kv0 = kb[d * 64 + (lane ^ (d & 63))];
    #pragma unroll
    for (int c = 0; c < 16; c++) accA[c] += qw[c * 128 + d] * kv0;
  }
  __syncthreads();
  for (int idx = tid; idx < 64 * 128; idx += 256) {
    int j = idx >> 7, d = idx & 127;
    int kidx = n * 64 + j;
    kb[d * 64 + (j ^ (d & 63))] = qk[base + (size_t)origp[kidx] * DD + d] * rnp[kidx];
  }
  __syncthreads();
  #pragma unroll 2
  for (int d = 0; d < 128; d++) {
    float kv0 = kb[d * 64 + (lane ^ (d & 63))];
    #pragma unroll
    for (int c = 0; c < 16; c++) accB[c] += qw[c * 128 + d] * kv0;
  }

  float pA[16], pB[16];
  #pragma unroll
  for (int ci = 0; ci < 16; ci++) {
    int qp = __shfl(qp_reg, ci);
    float sA = (kpA > qp) ? -1000000000.0f : ((kpA == qp) ? -100000.0f : accA[ci]);
    float sB = (kpB > qp) ? -1000000000.0f : ((kpB == qp) ? -100000.0f : accB[ci]);
    float m = fmaxf(sA, sB);
    #pragma unroll
    for (int o = 1; o < 64; o <<= 1) m = fmaxf(m, __shfl_xor(m, o));
    float eA = __expf(sA - m), eB = __expf(sB - m);
    float sum = eA + eB;
    #pragma unroll
    for (int o = 1; o < 64; o <<= 1) sum += __shfl_xor(sum, o);
    pA[ci] = eA / sum;
    pB[ci] = eB / sum;
    if (lane == 0) lg[(size_t)bh * RS + n * 64 + wave * 16 + ci] = m + __logf(sum);
  }
  __syncthreads();

  #pragma unroll
  for (int ci = 0; ci < 16; ci++) {
    qs[(wave * 16 + ci) * 128 + lane] = pA[ci];
    qs[(wave * 16 + ci) * 128 + 64 + lane] = pB[ci];
  }
  for (int idx = tid; idx < 64 * 128; idx += 256) {
    int j = idx >> 7, d = idx & 127;
    kb[j * 128 + d] = v[base + (size_t)origp[pn * 64 + j] * DD + d];
  }
  __syncthreads();
  float o0[16], o1[16];
  #pragma unroll
  for (int c = 0; c < 16; c++) { o0[c] = 0.f; o1[c] = 0.f; }
  #pragma unroll 2
  for (int j = 0; j < 64; j++) {
    float v0 = kb[j * 128 + lane];
    float v1 = kb[j * 128 + 64 + lane];
    #pragma unroll
    for (int c = 0; c < 16; c++) {
      float p = qw[c * 128 + j];
      o0[c] += p * v0; o1[c] += p * v1;
    }
  }
  __syncthreads();
  for (int idx = tid; idx < 64 * 128; idx += 256) {
    int j = idx >> 7, d = idx & 127;
    kb[j * 128 + d] = v[base + (size_t)origp[n * 64 + j] * DD + d];
  }
  __syncthreads();
  #pragma unroll 2
  for (int j = 0; j < 64; j++) {
    float v0 = kb[j * 128 + lane];
    float v1 = kb[j * 128 + 64 + lane];
    #pragma unroll
    for (int c = 0; c < 16; c++) {
      float p = qw[c * 128 + 64 + j];
      o0[c] += p * v0; o1[c] += p * v1;
    }
  }
  #pragma unroll
  for (int ci = 0; ci < 16; ci++) {
    size_t off = ((size_t)bh * RS + n * 64 + wave * 16 + ci) * DH;
    osort[off + lane] = o0[ci];
    osort[off + 64 + lane] = o1[ci];
  }
}

// ---------------------------------------------------------------------------
__global__ __launch_bounds__(256) void unsort_kernel(const float* __restrict__ osort,
                                                     const float* __restrict__ lg,
                                                     const int* __restrict__ undo,
                                                     float* __restrict__ attn) {
  int gid = blockIdx.x * 4 + (threadIdx.x >> 6);
  int lane = threadIdx.x & 63;
  int bh = gid >> 12;
  int s = gid & (SS - 1);
  int b = bh >> 3, h = bh & 7;
  int k0 = undo[(size_t)bh * RS + s];
  int k1 = undo[(size_t)bh * RS + SS + s];
  float l0 = lg[(size_t)bh * RS + k0], l1 = lg[(size_t)bh * RS + k1];
  float m = fmaxf(l0, l1);
  float e0 = __expf(l0 - m), e1 = __expf(l1 - m);
  float inv = 1.0f / (e0 + e1);
  float w0 = e0 * inv, w1 = e1 * inv;
  const float* r0 = osort + ((size_t)bh * RS + k0) * DH;
  const float* r1 = osort + ((size_t)bh * RS + k1) * DH;
  float* outp = attn + ((size_t)(b * SS + s)) * DD + h * DH;
  outp[lane]      = w0 * r0[lane]      + w1 * r1[lane];
  outp[lane + 64] = w0 * r0[lane + 64] + w1 * r1[lane + 64];
}

// ---------------------------------------------------------------------------
__global__ __launch_bounds__(256) void softmax_b_kernel(const float* __restrict__ logits,
                                                        const float* __restrict__ bout,
                                                        float* __restrict__ out) {
  int i = blockIdx.x * 256 + threadIdx.x;
  if (i >= SS * VV) return;
  int s = i / VV, vv = i - s * VV;
  float bvv = bout[vv];
  float l0 = logits[(size_t)s * VP + vv] + bvv;
  float l1 = logits[(size_t)(SS + s) * VP + vv] + bvv;
  float m = fmaxf(l0, l1);
  float e0 = __expf(l0 - m), e1 = __expf(l1 - m);
  float inv = 1.0f / (e0 + e1);
  out[(size_t)s * VV + vv] = e0 * inv;
  out[(size_t)(SS + s) * VV + vv] = e1 * inv;
}

// ---------------------------------------------------------------------------
// Workspace layout — total extent 237,502,464 B (R1/R4 proven footprint):
//   x1, x2, h: 3*NX f32; pool: 4*NX f32 (phase-aliased); misc 2.6 MB after.
//   Weight bf16 planes AND sort counts squat in pool[2NX..) (osort region)
//   only while osort is dead.
extern "C" void kernel_launch(void* const* d_in, const int* in_sizes, int n_in,
                              void* d_out, int out_size, void* d_ws, size_t ws_size,
                              hipStream_t stream) {
  (void)in_sizes; (void)n_in; (void)out_size; (void)ws_size;
  const float* x     = (const float*)d_in[0];
  const float* ln1_g = (const float*)d_in[1];
  const float* ln1_b = (const float*)d_in[2];
  const float* Wqk   = (const float*)d_in[3];
  const float* Wv    = (const float*)d_in[4];
  const float* Wo    = (const float*)d_in[5];
  const float* rot   = (const float*)d_in[6];
  const float* ln2_g = (const float*)d_in[7];
  const float* ln2_b = (const float*)d_in[8];
  const float* W1    = (const float*)d_in[9];
  const float* b1    = (const float*)d_in[10];
  const float* W2    = (const float*)d_in[11];
  const float* b2    = (const float*)d_in[12];
  const float* lnf_g = (const float*)d_in[13];
  const float* lnf_b = (const float*)d_in[14];
  const float* Wout  = (const float*)d_in[15];
  const float* bout  = (const float*)d_in[16];

  const size_t NX = (size_t)MROWS * DD;            // 8,388,608
  float* x1 = (float*)d_ws;
  float* x2 = x1 + NX;
  float* h  = x2 + NX;
  float* pool = h + NX;                            // 4*NX floats
  float* qkb   = pool;
  float* vb    = pool + NX;
  float* osort = pool + 2*NX;
  float* ff    = pool;                             // [8192][2048] f32, FFN K-half
  float* hcat  = pool;                             // [8192][2048] f32, head phase
  unsigned short* wt = (unsigned short*)(pool + 2*NX);   // weight squat region
  int* counts = (int*)(pool + 2*NX + 2097152);     // sort counts (1 MB), dead-osort squat
  float* after = pool + 4*NX;
  float* lgb = after;
  float* rno = lgb + (size_t)BH * RS;
  int* orig = (int*)(rno + (size_t)BH * RS);
  int* undo = orig + (size_t)BH * RS;
  int* ids  = undo + (size_t)BH * RS;
  float* logitsP = h;                              // [8192][VP] f32, head phase

  const size_t BP_D = (size_t)DD * DD;             // 1,048,576 (qk/v/wo plane stride)

  init_x_kernel<<<(int)(NX / 256), 256, 0, stream>>>(x, x1, x2);

  for (int l = 0; l < LL; l++) {
    // --- attention ---
    ln_kernel<<<MROWS, 256, 0, stream>>>(x2, ln1_g + l*DD, ln1_b + l*DD, h);

    // qk (bucket-critical, always 6-term). wt squats where osort will later live.
    wconv_kernel<3><<<dim3(32, 32), 256, 0, stream>>>(Wqk + (size_t)l*DD*DD, wt, DD, DD, DD, DD);
    mgemmf_kernel<true,0,false,false><<<dim3(8, 64), 256, 0, stream>>>(
        h, wt, nullptr, qkb, MROWS, DD, DD, BP_D);

    // v: layer 0 bucket-critical (feeds residual -> layer1 buckets), layer 1 relaxed
    if (l == 0) {
      wconv_kernel<3><<<dim3(32, 32), 256, 0, stream>>>(Wv + (size_t)l*DD*DD, wt, DD, DD, DD, DD);
      mgemmf_kernel<true,0,false,false><<<dim3(8, 64), 256, 0, stream>>>(
          h, wt, nullptr, vb, MROWS, DD, DD, BP_D);
    } else {
      wconv_kernel<1><<<dim3(32, 32), 256, 0, stream>>>(Wv + (size_t)l*DD*DD, wt, DD, DD, DD, DD);
      mgemmf_kernel<false,0,false,false><<<dim3(8, 64), 256, 0, stream>>>(
          h, wt, nullptr, vb, MROWS, DD, DD, BP_D);
    }

    bucket_kernel<<<BB*HH*SS, 64, 0, stream>>>(qkb, rot + (size_t)l*HH*DH*RR*64, ids);

    // parallel stable counting sort (counts squat in dead wt/osort region)
    hipMemsetAsync(counts, 0, (size_t)BH * RR * 64 * 128 * sizeof(int), stream);
    sort_count_kernel<<<512, 256, 0, stream>>>(ids, counts);
    sort_prefix_kernel<<<BH*RR, 128, 0, stream>>>(counts);
    sort_scatter_kernel<<<512, 256, 0, stream>>>(ids, counts, orig, undo);

    rnorm_kernel<<<BH*RS/4, 256, 0, stream>>>(qkb, orig, rno);
    attn_kernel<<<BH*NC, 256, 0, stream>>>(qkb, vb, orig, rno, osort, lgb);   // writes osort
    unsort_kernel<<<BH*SS/4, 256, 0, stream>>>(osort, lgb, undo, h);          // osort dead after

    // Wo (wt overwrites dead osort)
    if (l == 0) {
      wconv_kernel<3><<<dim3(32, 32), 256, 0, stream>>>(Wo + (size_t)l*DD*DD, wt, DD, DD, DD, DD);
      mgemmf_kernel<true,1,false,false><<<dim3(8, 64), 256, 0, stream>>>(
          h, wt, nullptr, x1, MROWS, DD, DD, BP_D);
    } else {
      wconv_kernel<1><<<dim3(32, 32), 256, 0, stream>>>(Wo + (size_t)l*DD*DD, wt, DD, DD, DD, DD);
      mgemmf_kernel<false,1,false,false><<<dim3(8, 64), 256, 0, stream>>>(
          h, wt, nullptr, x1, MROWS, DD, DD, BP_D);
    }

    // --- FFN, split into two FF-halves of 2048 so ff fits in pool[0,2NX) ---
    ln_kernel<<<MROWS, 256, 0, stream>>>(x1, ln2_g + l*DD, ln2_b + l*DD, h);
    for (int hf = 0; hf < 2; hf++) {
      const float* W1h = W1 + (size_t)l*DD*FFD + (size_t)hf*2048;     // [1024][·] cols half
      const float* W2h = W2 + (size_t)l*FFD*DD + (size_t)hf*2048*DD;  // rows half, [2048][1024]
      unsigned short* wt1 = wt;                       // [3][2048][1024] = 12.6 MB
      unsigned short* wt2 = wt + 3u*2097152u;         // [3][1024][2048] = 12.6 MB
      if (l == 0) {
        wconv_kernel<3><<<dim3(64, 32), 256, 0, stream>>>(W1h, wt1, DD, 2048, 2048, FFD);
        mgemmf_kernel<true,0,true,true><<<dim3(16, 64), 256, 0, stream>>>(
            h, wt1, b1 + (size_t)l*FFD + hf*2048, ff, MROWS, 2048, DD, 2097152u);
        wconv_kernel<3><<<dim3(32, 64), 256, 0, stream>>>(W2h, wt2, 2048, DD, DD, DD);
        if (hf == 0)
          mgemmf_kernel<true,1,true,false><<<dim3(8, 64), 256, 0, stream>>>(
              ff, wt2, b2 + (size_t)l*DD, x2, MROWS, DD, 2048, 2097152u);
        else
          mgemmf_kernel<true,1,false,false><<<dim3(8, 64), 256, 0, stream>>>(
              ff, wt2, nullptr, x2, MROWS, DD, 2048, 2097152u);
      } else {
        wconv_kernel<1><<<dim3(64, 32), 256, 0, stream>>>(W1h, wt1, DD, 2048, 2048, FFD);
        mgemmf_kernel<false,0,true,true><<<dim3(16, 64), 256, 0, stream>>>(
            h, wt1, b1 + (size_t)l*FFD + hf*2048, ff, MROWS, 2048, DD, 2097152u);
        wconv_kernel<1><<<dim3(32, 64), 256, 0, stream>>>(W2h, wt2, 2048, DD, DD, DD);
        if (hf == 0)
          mgemmf_kernel<false,1,true,false><<<dim3(8, 64), 256, 0, stream>>>(
              ff, wt2, b2 + (size_t)l*DD, x2, MROWS, DD, 2048, 2097152u);
        else
          mgemmf_kernel<false,1,false,false><<<dim3(8, 64), 256, 0, stream>>>(
              ff, wt2, nullptr, x2, MROWS, DD, 2048, 2097152u);
      }
    }
  }

  // --- head ---
  ln_concat_kernel<<<MROWS, 256, 0, stream>>>(x1, x2, lnf_g, lnf_b, hcat);
  wconv_kernel<1><<<dim3(12, 64), 256, 0, stream>>>(Wout, wt, 2*DD, VV, VP, VV);
  mgemmf_kernel<false,0,false,false><<<dim3(3, 64), 256, 0, stream>>>(
      hcat, wt, nullptr, logitsP, MROWS, VP, 2*DD, 0u);
  softmax_b_kernel<<<(SS*VV + 255)/256, 256, 0, stream>>>(logitsP, bout, (float*)d_out);
}

// Round 6
// 2583.454 us; speedup vs baseline: 3.2916x; 1.2148x over previous
//
#include <hip/hip_runtime.h>
#include <hip/hip_fp16.h>
#include <math.h>

#define BB 2
#define SS 4096
#define DD 1024
#define HH 8
#define DH 128
#define RR 2
#define CC 64
#define NBUCK 128
#define LL 2
#define FFD 4096
#define VV 258
#define VP 384            // padded vocab for head GEMM (multiple of 128)
#define RS (RR*SS)        // 8192
#define NC (RS/CC)        // 128
#define BH (BB*HH)        // 16
#define MROWS (BB*SS)     // 8192

// scale 2^8 on both operand splits; descale 2^-16 in epilogue (fp16 denorm guard)
#define SCF 256.0f
#define DSCF (1.0f/65536.0f)

typedef __attribute__((ext_vector_type(8))) _Float16 v8h;
typedef __attribute__((ext_vector_type(4))) _Float16 v4h;
typedef __attribute__((ext_vector_type(4))) float v4f;

// ---------------------------------------------------------------------------
__device__ __forceinline__ void gld16(const void* g, void* l) {
  __builtin_amdgcn_global_load_lds((const __attribute__((address_space(1))) void*)g,
                                   (__attribute__((address_space(3))) void*)l, 16, 0, 0);
}

// ---------------------------------------------------------------------------
__device__ __forceinline__ void block_sum2(float& s, float& s2) {
  #pragma unroll
  for (int o = 1; o < 64; o <<= 1) { s += __shfl_xor(s, o); s2 += __shfl_xor(s2, o); }
  __shared__ float rs[4], rq[4];
  int wave = threadIdx.x >> 6;
  if ((threadIdx.x & 63) == 0) { rs[wave] = s; rq[wave] = s2; }
  __syncthreads();
  s  = rs[0] + rs[1] + rs[2] + rs[3];
  s2 = rq[0] + rq[1] + rq[2] + rq[3];
}

// ---------------------------------------------------------------------------
__global__ __launch_bounds__(256) void init_x_kernel(const float* __restrict__ x,
                                                     float* __restrict__ x1,
                                                     float* __restrict__ x2) {
  size_t i = (size_t)blockIdx.x * 256 + threadIdx.x;
  float v = x[i];
  x1[i] = v; x2[i] = v;
}

// ---------------------------------------------------------------------------
// LayerNorm over D=1024 -> scaled fp16 2-plane split (plane stride MROWS*DD)
__global__ __launch_bounds__(256) void ln_split_kernel(const float* __restrict__ x,
                                                       const float* __restrict__ g,
                                                       const float* __restrict__ bta,
                                                       _Float16* __restrict__ out) {
  int row = blockIdx.x;
  int t = threadIdx.x;
  float4 xv = ((const float4*)(x + (size_t)row * DD))[t];
  float s  = xv.x + xv.y + xv.z + xv.w;
  float s2 = xv.x*xv.x + xv.y*xv.y + xv.z*xv.z + xv.w*xv.w;
  block_sum2(s, s2);
  float mu   = s * (1.0f / DD);
  float var  = fmaxf(s2 * (1.0f / DD) - mu * mu, 0.0f);
  float rstd = rsqrtf(var + 1e-12f);
  float4 gv = ((const float4*)g)[t];
  float4 bv = ((const float4*)bta)[t];
  float4 sv;
  sv.x = ((xv.x - mu) * rstd * gv.x + bv.x) * SCF;
  sv.y = ((xv.y - mu) * rstd * gv.y + bv.y) * SCF;
  sv.z = ((xv.z - mu) * rstd * gv.z + bv.z) * SCF;
  sv.w = ((xv.w - mu) * rstd * gv.w + bv.w) * SCF;
  v4h h0, h1;
  h0[0]=(_Float16)sv.x; h0[1]=(_Float16)sv.y; h0[2]=(_Float16)sv.z; h0[3]=(_Float16)sv.w;
  h1[0]=(_Float16)(sv.x-(float)h0[0]); h1[1]=(_Float16)(sv.y-(float)h0[1]);
  h1[2]=(_Float16)(sv.z-(float)h0[2]); h1[3]=(_Float16)(sv.w-(float)h0[3]);
  const size_t PLN = (size_t)MROWS * DD;
  size_t base = (size_t)row * DD + t * 4;
  *(v4h*)(out + base) = h0;
  *(v4h*)(out + PLN + base) = h1;
}

// LayerNorm over concat([x1,x2]) (2048) -> scaled fp16 2-plane split
__global__ __launch_bounds__(256) void ln_concat_split_kernel(const float* __restrict__ x1,
                                                              const float* __restrict__ x2,
                                                              const float* __restrict__ g,
                                                              const float* __restrict__ bta,
                                                              _Float16* __restrict__ out) {
  int row = blockIdx.x;
  int t = threadIdx.x;
  float4 a = ((const float4*)(x1 + (size_t)row * DD))[t];
  float4 b = ((const float4*)(x2 + (size_t)row * DD))[t];
  float s  = a.x + a.y + a.z + a.w + b.x + b.y + b.z + b.w;
  float s2 = a.x*a.x + a.y*a.y + a.z*a.z + a.w*a.w
           + b.x*b.x + b.y*b.y + b.z*b.z + b.w*b.w;
  block_sum2(s, s2);
  float mu   = s * (1.0f / (2*DD));
  float var  = fmaxf(s2 * (1.0f / (2*DD)) - mu * mu, 0.0f);
  float rstd = rsqrtf(var + 1e-12f);
  float4 g1 = ((const float4*)g)[t];
  float4 b1v = ((const float4*)bta)[t];
  float4 g2 = ((const float4*)g)[256 + t];
  float4 b2v = ((const float4*)bta)[256 + t];
  const size_t PLN = (size_t)MROWS * (2*DD);
  float4 s1, s2v;
  s1.x = ((a.x-mu)*rstd*g1.x + b1v.x)*SCF;  s1.y = ((a.y-mu)*rstd*g1.y + b1v.y)*SCF;
  s1.z = ((a.z-mu)*rstd*g1.z + b1v.z)*SCF;  s1.w = ((a.w-mu)*rstd*g1.w + b1v.w)*SCF;
  s2v.x = ((b.x-mu)*rstd*g2.x + b2v.x)*SCF; s2v.y = ((b.y-mu)*rstd*g2.y + b2v.y)*SCF;
  s2v.z = ((b.z-mu)*rstd*g2.z + b2v.z)*SCF; s2v.w = ((b.w-mu)*rstd*g2.w + b2v.w)*SCF;
  v4h h0, h1;
  size_t base = (size_t)row * (2*DD) + t * 4;
  h0[0]=(_Float16)s1.x; h0[1]=(_Float16)s1.y; h0[2]=(_Float16)s1.z; h0[3]=(_Float16)s1.w;
  h1[0]=(_Float16)(s1.x-(float)h0[0]); h1[1]=(_Float16)(s1.y-(float)h0[1]);
  h1[2]=(_Float16)(s1.z-(float)h0[2]); h1[3]=(_Float16)(s1.w-(float)h0[3]);
  *(v4h*)(out + base) = h0;
  *(v4h*)(out + PLN + base) = h1;
  h0[0]=(_Float16)s2v.x; h0[1]=(_Float16)s2v.y; h0[2]=(_Float16)s2v.z; h0[3]=(_Float16)s2v.w;
  h1[0]=(_Float16)(s2v.x-(float)h0[0]); h1[1]=(_Float16)(s2v.y-(float)h0[1]);
  h1[2]=(_Float16)(s2v.z-(float)h0[2]); h1[3]=(_Float16)(s2v.w-(float)h0[3]);
  *(v4h*)(out + base + DD) = h0;
  *(v4h*)(out + PLN + base + DD) = h1;
}

// ---------------------------------------------------------------------------
// weight convert fp32 W[K][·] (row stride ldw) cols [0,N) -> scaled fp16
// 2-plane split Wt[2][Npad][K] (zero pad n>=N)
__global__ __launch_bounds__(256) void wconv_kernel(const float* __restrict__ W,
                                                    _Float16* __restrict__ Wt,
                                                    int K, int N, int Npad, int ldw) {
  __shared__ float tile[32][33];
  int n0 = blockIdx.x * 32, k0 = blockIdx.y * 32;
  int tid = threadIdx.x;
  #pragma unroll
  for (int i = 0; i < 4; i++) {
    int idx = i*256 + tid;
    int kk = idx >> 5, nn = idx & 31;
    float v = 0.0f;
    if (n0 + nn < N) v = W[(size_t)(k0 + kk) * ldw + n0 + nn];
    tile[kk][nn] = v;
  }
  __syncthreads();
  size_t NKs = (size_t)Npad * K;
  #pragma unroll
  for (int i = 0; i < 4; i++) {
    int idx = i*256 + tid;
    int nn = idx >> 5, kk = idx & 31;
    float s = tile[kk][nn] * SCF;
    size_t off = (size_t)(n0 + nn) * K + k0 + kk;
    _Float16 h0 = (_Float16)s;
    _Float16 h1 = (_Float16)(s - (float)h0);
    Wt[off] = h0;
    Wt[NKs + off] = h1;
  }
}

// ---------------------------------------------------------------------------
// fp16x2 MFMA GEMM. A [PL][M][K] fp16 (plane stride aplane), scaled x256;
// Bt [PL][N][K] fp16 (plane stride bplane), scaled x256.
// PL=2: 4-product QUAD (fp32-equivalent, ~2.4e-7 rel); PL=1: single product.
// CMODE: 0 = store f32, 1 = accumulate f32, 2 = split-store fp16 2-plane
// (scaled, plane stride M*N). 128x128 tile, BK=32, 4 waves 2x2.
template<int PL, int CMODE, bool BIAS, bool RELU>
__global__ __launch_bounds__(256) void qgemm_kernel(const _Float16* __restrict__ A,
                                                    const _Float16* __restrict__ Bt,
                                                    const float* __restrict__ bias,
                                                    void* __restrict__ Cv,
                                                    int M, int N, int K,
                                                    size_t aplane, size_t bplane) {
  __shared__ __align__(16) _Float16 As[2*128*32];   // 16 KB (plane1 unused if PL=1)
  __shared__ __align__(16) _Float16 Bs[2*128*32];   // 16 KB
  int tid = threadIdx.x, lane = tid & 63, wave = tid >> 6;
  int m0 = blockIdx.y * 128, n0 = blockIdx.x * 128;
  int wm = (wave & 1) * 64, wn = (wave >> 1) * 64;
  int lm = lane & 15, quad = lane >> 4;
  const int NCH = (PL == 2) ? 8 : 4;                // chunks per wave (32 / 16 total)
  const int ACH = (PL == 2) ? 16 : 8;               // A chunk count
  v4f acc[4][4];
  #pragma unroll
  for (int i = 0; i < 4; i++)
    #pragma unroll
    for (int j = 0; j < 4; j++) acc[i][j] = (v4f)0.0f;

  for (int k0 = 0; k0 < K; k0 += 32) {
    #pragma unroll
    for (int i = 0; i < NCH; i++) {
      int c = wave * NCH + i;
      // chunk layout: plane p slab = 8 chunks of 16 rows x 32 cols fp16 (1 KB)
      if (c < ACH) {
        int p = c >> 3, q = c & 7;
        int row = q * 16 + (lane >> 2), col = (lane & 3) * 8;
        gld16(A + (size_t)p * aplane + (size_t)(m0 + row) * K + k0 + col,
              (char*)As + (size_t)c * 1024);
      } else {
        int cb = c - ACH;
        int p = cb >> 3, q = cb & 7;
        int row = q * 16 + (lane >> 2), col = (lane & 3) * 8;
        gld16(Bt + (size_t)p * bplane + (size_t)(n0 + row) * K + k0 + col,
              (char*)Bs + (size_t)cb * 1024);
      }
    }
    __syncthreads();
    v8h a[4][2], b[4][2];
    #pragma unroll
    for (int ni = 0; ni < 4; ni++) {
      int boff = (wn + ni*16 + lm) * 32 + quad * 8;
      b[ni][0] = *(const v8h*)&Bs[boff];
      if (PL == 2) b[ni][1] = *(const v8h*)&Bs[4096 + boff];
    }
    #pragma unroll
    for (int mi = 0; mi < 4; mi++) {
      int aoff = (wm + mi*16 + lm) * 32 + quad * 8;
      a[mi][0] = *(const v8h*)&As[aoff];
      if (PL == 2) a[mi][1] = *(const v8h*)&As[4096 + aoff];
    }
    #pragma unroll
    for (int mi = 0; mi < 4; mi++) {
      #pragma unroll
      for (int ni = 0; ni < 4; ni++) {
        v4f c0 = acc[mi][ni];
        c0 = __builtin_amdgcn_mfma_f32_16x16x32_f16(a[mi][0], b[ni][0], c0, 0, 0, 0);
        if (PL == 2) {
          c0 = __builtin_amdgcn_mfma_f32_16x16x32_f16(a[mi][0], b[ni][1], c0, 0, 0, 0);
          c0 = __builtin_amdgcn_mfma_f32_16x16x32_f16(a[mi][1], b[ni][0], c0, 0, 0, 0);
          c0 = __builtin_amdgcn_mfma_f32_16x16x32_f16(a[mi][1], b[ni][1], c0, 0, 0, 0);
        }
        acc[mi][ni] = c0;
      }
    }
    __syncthreads();
  }

  float* Cf = (float*)Cv;
  _Float16* Ch = (_Float16*)Cv;
  const size_t cplane = (size_t)M * N;
  #pragma unroll
  for (int mi = 0; mi < 4; mi++) {
    int rbase = m0 + wm + mi*16 + quad*4;
    #pragma unroll
    for (int ni = 0; ni < 4; ni++) {
      int col = n0 + wn + ni*16 + lm;
      float bv = BIAS ? bias[col] : 0.0f;
      #pragma unroll
      for (int r = 0; r < 4; r++) {
        float val = acc[mi][ni][r] * DSCF + bv;
        if (RELU) val = fmaxf(val, 0.0f);
        size_t off = (size_t)(rbase + r) * N + col;
        if (CMODE == 0) Cf[off] = val;
        else if (CMODE == 1) Cf[off] += val;
        else {
          float s = val * SCF;
          _Float16 h0 = (_Float16)s;
          _Float16 h1 = (_Float16)(s - (float)h0);
          Ch[off] = h0;
          Ch[cplane + off] = h1;
        }
      }
    }
  }
}

// ---------------------------------------------------------------------------
// buckets: one wave per (b,h,s); fp32 accumulation (err ~7e-7 << margin floor)
__global__ __launch_bounds__(64) void bucket_kernel(const float* __restrict__ qk,
                                                    const float* __restrict__ rot,
                                                    int* __restrict__ ids) {
  int blk = blockIdx.x;
  int s = blk & (SS - 1);
  int bh = blk >> 12;
  int b = bh >> 3, h = bh & 7;
  int lane = threadIdx.x;
  __shared__ float qv[DH];
  const float* qrow = qk + ((size_t)(b * SS + s)) * DD + h * DH;
  qv[lane] = qrow[lane];
  qv[lane + 64] = qrow[lane + 64];
  __syncthreads();
  const float* rh = rot + (size_t)h * (DH * RR * 64);
  for (int r = 0; r < RR; r++) {
    const float* rp = rh + r * 64 + lane;
    float acc = 0.0f;
    #pragma unroll 8
    for (int d = 0; d < DH; d++) acc += qv[d] * rp[(size_t)d * 128];
    float bvv; int bi;
    if (acc >= -acc) { bvv = acc; bi = lane; } else { bvv = -acc; bi = 64 + lane; }
    #pragma unroll
    for (int o = 1; o < 64; o <<= 1) {
      float ov = __shfl_xor(bvv, o);
      int oi = __shfl_xor(bi, o);
      if (ov > bvv || (ov == bvv && oi < bi)) { bvv = ov; bi = oi; }
    }
    if (lane == 0) ids[((size_t)bh * RR + r) * SS + s] = bi + r * NBUCK;
  }
}

// ---------------------------------------------------------------------------
// Parallel stable counting sort (R5-verified, bit-exact vs argsort)
__global__ __launch_bounds__(256) void sort_count_kernel(const int* __restrict__ ids,
                                                         int* __restrict__ counts) {
  int w = blockIdx.x * 4 + (threadIdx.x >> 6);
  int lane = threadIdx.x & 63;
  int bhr = w >> 6, seg = w & 63;
  int id = ids[(size_t)bhr * SS + seg * 64 + lane];
  int bin = id & 127;
  unsigned long long eq = ~0ull;
  #pragma unroll
  for (int bit = 0; bit < 7; bit++) {
    unsigned long long bal = __ballot((bin >> bit) & 1);
    eq &= ((bin >> bit) & 1) ? bal : ~bal;
  }
  int rank = __popcll(eq & ((1ull << lane) - 1ull));
  if (rank == 0)
    counts[((size_t)bhr * 64 + seg) * 128 + bin] = __popcll(eq);
}

__global__ __launch_bounds__(128) void sort_prefix_kernel(int* __restrict__ counts) {
  int bhr = blockIdx.x;
  int bin = threadIdx.x;
  int r = bhr & 1;
  int* cp = counts + (size_t)bhr * 64 * 128;
  int total = 0;
  for (int seg = 0; seg < 64; seg++) total += cp[seg * 128 + bin];
  __shared__ int tot[128];
  tot[bin] = total;
  __syncthreads();
  for (int off = 1; off < 128; off <<= 1) {
    int t = (bin >= off) ? tot[bin - off] : 0;
    __syncthreads();
    tot[bin] += t;
    __syncthreads();
  }
  int run = tot[bin] - total + r * SS;
  for (int seg = 0; seg < 64; seg++) {
    int c = cp[seg * 128 + bin];
    cp[seg * 128 + bin] = run;
    run += c;
  }
}

__global__ __launch_bounds__(256) void sort_scatter_kernel(const int* __restrict__ ids,
                                                           const int* __restrict__ offs,
                                                           int* __restrict__ orig,
                                                           int* __restrict__ undo) {
  int w = blockIdx.x * 4 + (threadIdx.x >> 6);
  int lane = threadIdx.x & 63;
  int bhr = w >> 6, seg = w & 63;
  int s = seg * 64 + lane;
  int id = ids[(size_t)bhr * SS + s];
  int bin = id & 127;
  unsigned long long eq = ~0ull;
  #pragma unroll
  for (int bit = 0; bit < 7; bit++) {
    unsigned long long bal = __ballot((bin >> bit) & 1);
    eq &= ((bin >> bit) & 1) ? bal : ~bal;
  }
  int rank = __popcll(eq & ((1ull << lane) - 1ull));
  int o = offs[((size_t)bhr * 64 + seg) * 128 + bin] + rank;
  int bh = bhr >> 1, r = bhr & 1;
  orig[(size_t)bh * RS + o] = s;
  undo[(size_t)bh * RS + r * SS + s] = o;
}

// ---------------------------------------------------------------------------
__global__ __launch_bounds__(256) void rnorm_kernel(const float* __restrict__ qk,
                                                    const int* __restrict__ orig,
                                                    float* __restrict__ rno) {
  int idx = blockIdx.x * 4 + (threadIdx.x >> 6);
  int lane = threadIdx.x & 63;
  int bh = idx >> 13;
  int k = idx & (RS - 1);
  int b = bh >> 3, h = bh & 7;
  int s = orig[(size_t)bh * RS + k];
  const float* row = qk + ((size_t)(b * SS + s)) * DD + h * DH;
  float x0 = row[lane], x1 = row[lane + 64];
  float ss = x0 * x0 + x1 * x1;
  #pragma unroll
  for (int o = 1; o < 64; o <<= 1) ss += __shfl_xor(ss, o);
  if (lane == 0)
    rno[(size_t)bh * RS + k] = rsqrtf(ss * (1.0f / DH) + 1e-6f) * 0.08838834764831845f;
}

// ---------------------------------------------------------------------------
// chunked attention, all fp32 (R1-verified)
__global__ __launch_bounds__(256) void attn_kernel(const float* __restrict__ qk,
                                                   const float* __restrict__ v,
                                                   const int* __restrict__ orig,
                                                   const float* __restrict__ rno,
                                                   float* __restrict__ osort,
                                                   float* __restrict__ lg) {
  __shared__ float qs[64 * 128];
  __shared__ float kb[128 * 64];
  int blk = blockIdx.x;
  int n = blk & (NC - 1);
  int bh = blk >> 7;
  int b = bh >> 3, h = bh & 7;
  int pn = (n + NC - 1) & (NC - 1);
  int tid = threadIdx.x;
  int wave = tid >> 6, lane = tid & 63;
  const int* origp = orig + (size_t)bh * RS;
  const float* rnp = rno + (size_t)bh * RS;
  const size_t base = (size_t)b * SS * DD + (size_t)h * DH;

  for (int idx = tid; idx < 64 * 128; idx += 256) {
    int c = idx >> 7, d = idx & 127;
    qs[idx] = qk[base + (size_t)origp[n * 64 + c] * DD + d];
  }
  for (int idx = tid; idx < 64 * 128; idx += 256) {
    int j = idx >> 7, d = idx & 127;
    int kidx = pn * 64 + j;
    kb[d * 64 + (j ^ (d & 63))] = qk[base + (size_t)origp[kidx] * DD + d] * rnp[kidx];
  }
  int kpA = origp[pn * 64 + lane];
  int kpB = origp[n * 64 + lane];
  int qp_reg = origp[n * 64 + wave * 16 + (lane & 15)];
  float accA[16], accB[16];
  #pragma unroll
  for (int c = 0; c < 16; c++) { accA[c] = 0.f; accB[c] = 0.f; }
  __syncthreads();

  const float* qw = qs + wave * (16 * 128);
  #pragma unroll 2
  for (int d = 0; d < 128; d++) {
    float kv0 = kb[d * 64 + (lane ^ (d & 63))];
    #pragma unroll
    for (int c = 0; c < 16; c++) accA[c] += qw[c * 128 + d] * kv0;
  }
  __syncthreads();
  for (int idx = tid; idx < 64 * 128; idx += 256) {
    int j = idx >> 7, d = idx & 127;
    int kidx = n * 64 + j;
    kb[d * 64 + (j ^ (d & 63))] = qk[base + (size_t)origp[kidx] * DD + d] * rnp[kidx];
  }
  __syncthreads();
  #pragma unroll 2
  for (int d = 0; d < 128; d++) {
    float kv0 = kb[d * 64 + (lane ^ (d & 63))];
    #pragma unroll
    for (int c = 0; c < 16; c++) accB[c] += qw[c * 128 + d] * kv0;
  }

  float pA[16], pB[16];
  #pragma unroll
  for (int ci = 0; ci < 16; ci++) {
    int qp = __shfl(qp_reg, ci);
    float sA = (kpA > qp) ? -1000000000.0f : ((kpA == qp) ? -100000.0f : accA[ci]);
    float sB = (kpB > qp) ? -1000000000.0f : ((kpB == qp) ? -100000.0f : accB[ci]);
    float m = fmaxf(sA, sB);
    #pragma unroll
    for (int o = 1; o < 64; o <<= 1) m = fmaxf(m, __shfl_xor(m, o));
    float eA = __expf(sA - m), eB = __expf(sB - m);
    float sum = eA + eB;
    #pragma unroll
    for (int o = 1; o < 64; o <<= 1) sum += __shfl_xor(sum, o);
    pA[ci] = eA / sum;
    pB[ci] = eB / sum;
    if (lane == 0) lg[(size_t)bh * RS + n * 64 + wave * 16 + ci] = m + __logf(sum);
  }
  __syncthreads();

  #pragma unroll
  for (int ci = 0; ci < 16; ci++) {
    qs[(wave * 16 + ci) * 128 + lane] = pA[ci];
    qs[(wave * 16 + ci) * 128 + 64 + lane] = pB[ci];
  }
  for (int idx = tid; idx < 64 * 128; idx += 256) {
    int j = idx >> 7, d = idx & 127;
    kb[j * 128 + d] = v[base + (size_t)origp[pn * 64 + j] * DD + d];
  }
  __syncthreads();
  float o0[16], o1[16];
  #pragma unroll
  for (int c = 0; c < 16; c++) { o0[c] = 0.f; o1[c] = 0.f; }
  #pragma unroll 2
  for (int j = 0; j < 64; j++) {
    float v0 = kb[j * 128 + lane];
    float v1 = kb[j * 128 + 64 + lane];
    #pragma unroll
    for (int c = 0; c < 16; c++) {
      float p = qw[c * 128 + j];
      o0[c] += p * v0; o1[c] += p * v1;
    }
  }
  __syncthreads();
  for (int idx = tid; idx < 64 * 128; idx += 256) {
    int j = idx >> 7, d = idx & 127;
    kb[j * 128 + d] = v[base + (size_t)origp[n * 64 + j] * DD + d];
  }
  __syncthreads();
  #pragma unroll 2
  for (int j = 0; j < 64; j++) {
    float v0 = kb[j * 128 + lane];
    float v1 = kb[j * 128 + 64 + lane];
    #pragma unroll
    for (int c = 0; c < 16; c++) {
      float p = qw[c * 128 + 64 + j];
      o0[c] += p * v0; o1[c] += p * v1;
    }
  }
  #pragma unroll
  for (int ci = 0; ci < 16; ci++) {
    size_t off = ((size_t)bh * RS + n * 64 + wave * 16 + ci) * DH;
    osort[off + lane] = o0[ci];
    osort[off + 64 + lane] = o1[ci];
  }
}

// ---------------------------------------------------------------------------
// unsort + round-combine -> scaled fp16 2-plane split in h region
__global__ __launch_bounds__(256) void unsort_split_kernel(const float* __restrict__ osort,
                                                           const float* __restrict__ lg,
                                                           const int* __restrict__ undo,
                                                           _Float16* __restrict__ attn) {
  int gid = blockIdx.x * 4 + (threadIdx.x >> 6);
  int lane = threadIdx.x & 63;
  int bh = gid >> 12;
  int s = gid & (SS - 1);
  int b = bh >> 3, h = bh & 7;
  int k0 = undo[(size_t)bh * RS + s];
  int k1 = undo[(size_t)bh * RS + SS + s];
  float l0 = lg[(size_t)bh * RS + k0], l1 = lg[(size_t)bh * RS + k1];
  float m = fmaxf(l0, l1);
  float e0 = __expf(l0 - m), e1 = __expf(l1 - m);
  float inv = 1.0f / (e0 + e1);
  float w0 = e0 * inv, w1 = e1 * inv;
  const float* r0 = osort + ((size_t)bh * RS + k0) * DH;
  const float* r1 = osort + ((size_t)bh * RS + k1) * DH;
  const size_t PLN = (size_t)MROWS * DD;
  _Float16* outp = attn + ((size_t)(b * SS + s)) * DD + h * DH;
  float sA = (w0 * r0[lane]      + w1 * r1[lane])      * SCF;
  float sB = (w0 * r0[lane + 64] + w1 * r1[lane + 64]) * SCF;
  _Float16 a0 = (_Float16)sA, b0 = (_Float16)sB;
  outp[lane] = a0;                 outp[lane + 64] = b0;
  outp[PLN + lane] = (_Float16)(sA - (float)a0);
  outp[PLN + lane + 64] = (_Float16)(sB - (float)b0);
}

// ---------------------------------------------------------------------------
__global__ __launch_bounds__(256) void softmax_b_kernel(const float* __restrict__ logits,
                                                        const float* __restrict__ bout,
                                                        float* __restrict__ out) {
  int i = blockIdx.x * 256 + threadIdx.x;
  if (i >= SS * VV) return;
  int s = i / VV, vv = i - s * VV;
  float bvv = bout[vv];
  float l0 = logits[(size_t)s * VP + vv] + bvv;
  float l1 = logits[(size_t)(SS + s) * VP + vv] + bvv;
  float m = fmaxf(l0, l1);
  float e0 = __expf(l0 - m), e1 = __expf(l1 - m);
  float inv = 1.0f / (e0 + e1);
  out[(size_t)s * VV + vv] = e0 * inv;
  out[(size_t)(SS + s) * VV + vv] = e1 * inv;
}

// ---------------------------------------------------------------------------
// Workspace layout — extent 237,502,464 B (R1/R4/R5 proven footprint):
//   x1, x2: 2*NX f32 | h: NX f32, reused as hs = [2][M][1024] fp16 (exact fit)
//   pool 4*NX f32: attn phase qkb[0,NX) vb[NX,2NX) osort[2NX,4NX);
//     FFN phase ff = [2][M][2048] fp16 split in pool[0,2NX) (exact fit),
//     weights wt squat in pool[2NX..) while osort dead; head: hcat split in
//     pool[0,2NX), wout in wt. counts (1MB) at pool+2NX+8MB (dead-phase squat).
//   misc (lgb/rno/orig/undo/ids) after pool.
extern "C" void kernel_launch(void* const* d_in, const int* in_sizes, int n_in,
                              void* d_out, int out_size, void* d_ws, size_t ws_size,
                              hipStream_t stream) {
  (void)in_sizes; (void)n_in; (void)out_size; (void)ws_size;
  const float* x     = (const float*)d_in[0];
  const float* ln1_g = (const float*)d_in[1];
  const float* ln1_b = (const float*)d_in[2];
  const float* Wqk   = (const float*)d_in[3];
  const float* Wv    = (const float*)d_in[4];
  const float* Wo    = (const float*)d_in[5];
  const float* rot   = (const float*)d_in[6];
  const float* ln2_g = (const float*)d_in[7];
  const float* ln2_b = (const float*)d_in[8];
  const float* W1    = (const float*)d_in[9];
  const float* b1    = (const float*)d_in[10];
  const float* W2    = (const float*)d_in[11];
  const float* b2    = (const float*)d_in[12];
  const float* lnf_g = (const float*)d_in[13];
  const float* lnf_b = (const float*)d_in[14];
  const float* Wout  = (const float*)d_in[15];
  const float* bout  = (const float*)d_in[16];

  const size_t NX = (size_t)MROWS * DD;            // 8,388,608
  float* x1 = (float*)d_ws;
  float* x2 = x1 + NX;
  float* h  = x2 + NX;
  _Float16* hs = (_Float16*)h;                     // [2][M][1024] fp16 (= NX f32)
  float* pool = h + NX;
  float* qkb   = pool;
  float* vb    = pool + NX;
  float* osort = pool + 2*NX;
  _Float16* ffh = (_Float16*)pool;                 // [2][M][2048] fp16 (= 2NX f32)
  _Float16* hcs = (_Float16*)pool;                 // [2][M][2048] fp16, head phase
  _Float16* wt = (_Float16*)(pool + 2*NX);         // weight squat region
  int* counts = (int*)(pool + 2*NX + 2097152);     // 1 MB, squat (dead phases only)
  float* after = pool + 4*NX;
  float* lgb = after;
  float* rno = lgb + (size_t)BH * RS;
  int* orig = (int*)(rno + (size_t)BH * RS);
  int* undo = orig + (size_t)BH * RS;
  int* ids  = undo + (size_t)BH * RS;
  float* logitsP = h;                              // [M][VP] f32, head phase

  const size_t AP_D  = NX;                         // hs plane stride (halves)
  const size_t AP_FF = (size_t)MROWS * 2048;       // ffh/hcs plane stride
  const size_t BP_D  = (size_t)DD * DD;            // [1024][1024] weight plane
  const size_t BP_W1 = (size_t)2048 * DD;          // [2048][1024]
  const size_t BP_W2 = (size_t)DD * 2048;          // [1024][2048]
  const size_t BP_HD = (size_t)VP * 2048;          // [384][2048]

  init_x_kernel<<<(int)(NX / 256), 256, 0, stream>>>(x, x1, x2);

  for (int l = 0; l < LL; l++) {
    // --- attention ---
    ln_split_kernel<<<MROWS, 256, 0, stream>>>(x2, ln1_g + l*DD, ln1_b + l*DD, hs);

    // qk (bucket-critical: QUAD fp16x2)
    wconv_kernel<<<dim3(32, 32), 256, 0, stream>>>(Wqk + (size_t)l*DD*DD, wt, DD, DD, DD, DD);
    qgemm_kernel<2,0,false,false><<<dim3(8, 64), 256, 0, stream>>>(
        hs, wt, nullptr, qkb, MROWS, DD, DD, AP_D, BP_D);

    // v: layer 0 bucket-critical (feeds residual -> layer1 buckets), layer 1 single
    wconv_kernel<<<dim3(32, 32), 256, 0, stream>>>(Wv + (size_t)l*DD*DD, wt, DD, DD, DD, DD);
    if (l == 0)
      qgemm_kernel<2,0,false,false><<<dim3(8, 64), 256, 0, stream>>>(
          hs, wt, nullptr, vb, MROWS, DD, DD, AP_D, BP_D);
    else
      qgemm_kernel<1,0,false,false><<<dim3(8, 64), 256, 0, stream>>>(
          hs, wt, nullptr, vb, MROWS, DD, DD, AP_D, BP_D);

    bucket_kernel<<<BB*HH*SS, 64, 0, stream>>>(qkb, rot + (size_t)l*HH*DH*RR*64, ids);

    hipMemsetAsync(counts, 0, (size_t)BH * RR * 64 * 128 * sizeof(int), stream);
    sort_count_kernel<<<512, 256, 0, stream>>>(ids, counts);
    sort_prefix_kernel<<<BH*RR, 128, 0, stream>>>(counts);
    sort_scatter_kernel<<<512, 256, 0, stream>>>(ids, counts, orig, undo);

    rnorm_kernel<<<BH*RS/4, 256, 0, stream>>>(qkb, orig, rno);
    attn_kernel<<<BH*NC, 256, 0, stream>>>(qkb, vb, orig, rno, osort, lgb);
    unsort_split_kernel<<<BH*SS/4, 256, 0, stream>>>(osort, lgb, undo, hs);   // osort dead

    // Wo
    wconv_kernel<<<dim3(32, 32), 256, 0, stream>>>(Wo + (size_t)l*DD*DD, wt, DD, DD, DD, DD);
    if (l == 0)
      qgemm_kernel<2,1,false,false><<<dim3(8, 64), 256, 0, stream>>>(
          hs, wt, nullptr, x1, MROWS, DD, DD, AP_D, BP_D);
    else
      qgemm_kernel<1,1,false,false><<<dim3(8, 64), 256, 0, stream>>>(
          hs, wt, nullptr, x1, MROWS, DD, DD, AP_D, BP_D);

    // --- FFN, two FF-halves of 2048 (ff split planes fit pool[0,2NX)) ---
    ln_split_kernel<<<MROWS, 256, 0, stream>>>(x1, ln2_g + l*DD, ln2_b + l*DD, hs);
    for (int hf = 0; hf < 2; hf++) {
      const float* W1h = W1 + (size_t)l*DD*FFD + (size_t)hf*2048;     // cols half
      const float* W2h = W2 + (size_t)l*FFD*DD + (size_t)hf*2048*DD;  // rows half
      _Float16* wt1 = wt;                        // [2][2048][1024] = 8 MB
      _Float16* wt2 = wt + 2u*2097152u;          // [2][1024][2048] = 8 MB
      wconv_kernel<<<dim3(64, 32), 256, 0, stream>>>(W1h, wt1, DD, 2048, 2048, FFD);
      wconv_kernel<<<dim3(32, 64), 256, 0, stream>>>(W2h, wt2, 2048, DD, DD, DD);
      if (l == 0) {
        qgemm_kernel<2,2,true,true><<<dim3(16, 64), 256, 0, stream>>>(
            hs, wt1, b1 + (size_t)l*FFD + hf*2048, ffh, MROWS, 2048, DD, AP_D, BP_W1);
        if (hf == 0)
          qgemm_kernel<2,1,true,false><<<dim3(8, 64), 256, 0, stream>>>(
              ffh, wt2, b2 + (size_t)l*DD, x2, MROWS, DD, 2048, AP_FF, BP_W2);
        else
          qgemm_kernel<2,1,false,false><<<dim3(8, 64), 256, 0, stream>>>(
              ffh, wt2, nullptr, x2, MROWS, DD, 2048, AP_FF, BP_W2);
      } else {
        qgemm_kernel<1,2,true,true><<<dim3(16, 64), 256, 0, stream>>>(
            hs, wt1, b1 + (size_t)l*FFD + hf*2048, ffh, MROWS, 2048, DD, AP_D, BP_W1);
        if (hf == 0)
          qgemm_kernel<1,1,true,false><<<dim3(8, 64), 256, 0, stream>>>(
              ffh, wt2, b2 + (size_t)l*DD, x2, MROWS, DD, 2048, AP_FF, BP_W2);
        else
          qgemm_kernel<1,1,false,false><<<dim3(8, 64), 256, 0, stream>>>(
              ffh, wt2, nullptr, x2, MROWS, DD, 2048, AP_FF, BP_W2);
      }
    }
  }

  // --- head ---
  ln_concat_split_kernel<<<MROWS, 256, 0, stream>>>(x1, x2, lnf_g, lnf_b, hcs);
  wconv_kernel<<<dim3(12, 64), 256, 0, stream>>>(Wout, wt, 2*DD, VV, VP, VV);
  qgemm_kernel<1,0,false,false><<<dim3(3, 64), 256, 0, stream>>>(
      hcs, wt, nullptr, logitsP, MROWS, VP, 2*DD, AP_FF, BP_HD);
  softmax_b_kernel<<<(SS*VV + 255)/256, 256, 0, stream>>>(logitsP, bout, (float*)d_out);
}

// Round 7
// 1948.844 us; speedup vs baseline: 4.3634x; 1.3256x over previous
//
#include <hip/hip_runtime.h>
#include <hip/hip_fp16.h>
#include <math.h>

#define BB 2
#define SS 4096
#define DD 1024
#define HH 8
#define DH 128
#define RR 2
#define CC 64
#define NBUCK 128
#define LL 2
#define FFD 4096
#define VV 258
#define VP 384            // padded vocab for head GEMM (multiple of 128)
#define RS (RR*SS)        // 8192
#define NC (RS/CC)        // 128
#define BH (BB*HH)        // 16
#define MROWS (BB*SS)     // 8192

// scale 2^8 on both operand splits; descale 2^-16 in epilogue (fp16 denorm guard)
#define SCF 256.0f
#define DSCF (1.0f/65536.0f)

typedef __attribute__((ext_vector_type(8))) _Float16 v8h;
typedef __attribute__((ext_vector_type(4))) _Float16 v4h;
typedef __attribute__((ext_vector_type(4))) float v4f;

// ---------------------------------------------------------------------------
__device__ __forceinline__ void gld16(const void* g, void* l) {
  __builtin_amdgcn_global_load_lds((const __attribute__((address_space(1))) void*)g,
                                   (__attribute__((address_space(3))) void*)l, 16, 0, 0);
}

// ---------------------------------------------------------------------------
__device__ __forceinline__ void block_sum2(float& s, float& s2) {
  #pragma unroll
  for (int o = 1; o < 64; o <<= 1) { s += __shfl_xor(s, o); s2 += __shfl_xor(s2, o); }
  __shared__ float rs[4], rq[4];
  int wave = threadIdx.x >> 6;
  if ((threadIdx.x & 63) == 0) { rs[wave] = s; rq[wave] = s2; }
  __syncthreads();
  s  = rs[0] + rs[1] + rs[2] + rs[3];
  s2 = rq[0] + rq[1] + rq[2] + rq[3];
}

// ---------------------------------------------------------------------------
__global__ __launch_bounds__(256) void init_x_kernel(const float* __restrict__ x,
                                                     float* __restrict__ x1,
                                                     float* __restrict__ x2) {
  size_t i = (size_t)blockIdx.x * 256 + threadIdx.x;
  float v = x[i];
  x1[i] = v; x2[i] = v;
}

// ---------------------------------------------------------------------------
// LayerNorm over D=1024 -> scaled fp16 2-plane split (plane stride MROWS*DD)
__global__ __launch_bounds__(256) void ln_split_kernel(const float* __restrict__ x,
                                                       const float* __restrict__ g,
                                                       const float* __restrict__ bta,
                                                       _Float16* __restrict__ out) {
  int row = blockIdx.x;
  int t = threadIdx.x;
  float4 xv = ((const float4*)(x + (size_t)row * DD))[t];
  float s  = xv.x + xv.y + xv.z + xv.w;
  float s2 = xv.x*xv.x + xv.y*xv.y + xv.z*xv.z + xv.w*xv.w;
  block_sum2(s, s2);
  float mu   = s * (1.0f / DD);
  float var  = fmaxf(s2 * (1.0f / DD) - mu * mu, 0.0f);
  float rstd = rsqrtf(var + 1e-12f);
  float4 gv = ((const float4*)g)[t];
  float4 bv = ((const float4*)bta)[t];
  float4 sv;
  sv.x = ((xv.x - mu) * rstd * gv.x + bv.x) * SCF;
  sv.y = ((xv.y - mu) * rstd * gv.y + bv.y) * SCF;
  sv.z = ((xv.z - mu) * rstd * gv.z + bv.z) * SCF;
  sv.w = ((xv.w - mu) * rstd * gv.w + bv.w) * SCF;
  v4h h0, h1;
  h0[0]=(_Float16)sv.x; h0[1]=(_Float16)sv.y; h0[2]=(_Float16)sv.z; h0[3]=(_Float16)sv.w;
  h1[0]=(_Float16)(sv.x-(float)h0[0]); h1[1]=(_Float16)(sv.y-(float)h0[1]);
  h1[2]=(_Float16)(sv.z-(float)h0[2]); h1[3]=(_Float16)(sv.w-(float)h0[3]);
  const size_t PLN = (size_t)MROWS * DD;
  size_t base = (size_t)row * DD + t * 4;
  *(v4h*)(out + base) = h0;
  *(v4h*)(out + PLN + base) = h1;
}

// LayerNorm over concat([x1,x2]) (2048) -> scaled fp16 2-plane split
__global__ __launch_bounds__(256) void ln_concat_split_kernel(const float* __restrict__ x1,
                                                              const float* __restrict__ x2,
                                                              const float* __restrict__ g,
                                                              const float* __restrict__ bta,
                                                              _Float16* __restrict__ out) {
  int row = blockIdx.x;
  int t = threadIdx.x;
  float4 a = ((const float4*)(x1 + (size_t)row * DD))[t];
  float4 b = ((const float4*)(x2 + (size_t)row * DD))[t];
  float s  = a.x + a.y + a.z + a.w + b.x + b.y + b.z + b.w;
  float s2 = a.x*a.x + a.y*a.y + a.z*a.z + a.w*a.w
           + b.x*b.x + b.y*b.y + b.z*b.z + b.w*b.w;
  block_sum2(s, s2);
  float mu   = s * (1.0f / (2*DD));
  float var  = fmaxf(s2 * (1.0f / (2*DD)) - mu * mu, 0.0f);
  float rstd = rsqrtf(var + 1e-12f);
  float4 g1 = ((const float4*)g)[t];
  float4 b1v = ((const float4*)bta)[t];
  float4 g2 = ((const float4*)g)[256 + t];
  float4 b2v = ((const float4*)bta)[256 + t];
  const size_t PLN = (size_t)MROWS * (2*DD);
  float4 s1, s2v;
  s1.x = ((a.x-mu)*rstd*g1.x + b1v.x)*SCF;  s1.y = ((a.y-mu)*rstd*g1.y + b1v.y)*SCF;
  s1.z = ((a.z-mu)*rstd*g1.z + b1v.z)*SCF;  s1.w = ((a.w-mu)*rstd*g1.w + b1v.w)*SCF;
  s2v.x = ((b.x-mu)*rstd*g2.x + b2v.x)*SCF; s2v.y = ((b.y-mu)*rstd*g2.y + b2v.y)*SCF;
  s2v.z = ((b.z-mu)*rstd*g2.z + b2v.z)*SCF; s2v.w = ((b.w-mu)*rstd*g2.w + b2v.w)*SCF;
  v4h h0, h1;
  size_t base = (size_t)row * (2*DD) + t * 4;
  h0[0]=(_Float16)s1.x; h0[1]=(_Float16)s1.y; h0[2]=(_Float16)s1.z; h0[3]=(_Float16)s1.w;
  h1[0]=(_Float16)(s1.x-(float)h0[0]); h1[1]=(_Float16)(s1.y-(float)h0[1]);
  h1[2]=(_Float16)(s1.z-(float)h0[2]); h1[3]=(_Float16)(s1.w-(float)h0[3]);
  *(v4h*)(out + base) = h0;
  *(v4h*)(out + PLN + base) = h1;
  h0[0]=(_Float16)s2v.x; h0[1]=(_Float16)s2v.y; h0[2]=(_Float16)s2v.z; h0[3]=(_Float16)s2v.w;
  h1[0]=(_Float16)(s2v.x-(float)h0[0]); h1[1]=(_Float16)(s2v.y-(float)h0[1]);
  h1[2]=(_Float16)(s2v.z-(float)h0[2]); h1[3]=(_Float16)(s2v.w-(float)h0[3]);
  *(v4h*)(out + base + DD) = h0;
  *(v4h*)(out + PLN + base + DD) = h1;
}

// ---------------------------------------------------------------------------
// weight convert fp32 W[K][·] (row stride ldw) cols [0,N) -> scaled fp16
// 2-plane split Wt[2][Npad][K] (zero pad n>=N)
__global__ __launch_bounds__(256) void wconv_kernel(const float* __restrict__ W,
                                                    _Float16* __restrict__ Wt,
                                                    int K, int N, int Npad, int ldw) {
  __shared__ float tile[32][33];
  int n0 = blockIdx.x * 32, k0 = blockIdx.y * 32;
  int tid = threadIdx.x;
  #pragma unroll
  for (int i = 0; i < 4; i++) {
    int idx = i*256 + tid;
    int kk = idx >> 5, nn = idx & 31;
    float v = 0.0f;
    if (n0 + nn < N) v = W[(size_t)(k0 + kk) * ldw + n0 + nn];
    tile[kk][nn] = v;
  }
  __syncthreads();
  size_t NKs = (size_t)Npad * K;
  #pragma unroll
  for (int i = 0; i < 4; i++) {
    int idx = i*256 + tid;
    int nn = idx >> 5, kk = idx & 31;
    float s = tile[kk][nn] * SCF;
    size_t off = (size_t)(n0 + nn) * K + k0 + kk;
    _Float16 h0 = (_Float16)s;
    _Float16 h1 = (_Float16)(s - (float)h0);
    Wt[off] = h0;
    Wt[NKs + off] = h1;
  }
}

// ---------------------------------------------------------------------------
// fp16x2 MFMA GEMM (R6-verified). PL=2: QUAD (fp32-equivalent); PL=1: single.
// CMODE: 0 store f32, 1 accumulate f32, 2 split-store fp16 2-plane.
template<int PL, int CMODE, bool BIAS, bool RELU>
__global__ __launch_bounds__(256) void qgemm_kernel(const _Float16* __restrict__ A,
                                                    const _Float16* __restrict__ Bt,
                                                    const float* __restrict__ bias,
                                                    void* __restrict__ Cv,
                                                    int M, int N, int K,
                                                    size_t aplane, size_t bplane) {
  __shared__ __align__(16) _Float16 As[2*128*32];
  __shared__ __align__(16) _Float16 Bs[2*128*32];
  int tid = threadIdx.x, lane = tid & 63, wave = tid >> 6;
  int m0 = blockIdx.y * 128, n0 = blockIdx.x * 128;
  int wm = (wave & 1) * 64, wn = (wave >> 1) * 64;
  int lm = lane & 15, quad = lane >> 4;
  const int NCH = (PL == 2) ? 8 : 4;
  const int ACH = (PL == 2) ? 16 : 8;
  v4f acc[4][4];
  #pragma unroll
  for (int i = 0; i < 4; i++)
    #pragma unroll
    for (int j = 0; j < 4; j++) acc[i][j] = (v4f)0.0f;

  for (int k0 = 0; k0 < K; k0 += 32) {
    #pragma unroll
    for (int i = 0; i < NCH; i++) {
      int c = wave * NCH + i;
      if (c < ACH) {
        int p = c >> 3, q = c & 7;
        int row = q * 16 + (lane >> 2), col = (lane & 3) * 8;
        gld16(A + (size_t)p * aplane + (size_t)(m0 + row) * K + k0 + col,
              (char*)As + (size_t)c * 1024);
      } else {
        int cb = c - ACH;
        int p = cb >> 3, q = cb & 7;
        int row = q * 16 + (lane >> 2), col = (lane & 3) * 8;
        gld16(Bt + (size_t)p * bplane + (size_t)(n0 + row) * K + k0 + col,
              (char*)Bs + (size_t)cb * 1024);
      }
    }
    __syncthreads();
    v8h a[4][2], b[4][2];
    #pragma unroll
    for (int ni = 0; ni < 4; ni++) {
      int boff = (wn + ni*16 + lm) * 32 + quad * 8;
      b[ni][0] = *(const v8h*)&Bs[boff];
      if (PL == 2) b[ni][1] = *(const v8h*)&Bs[4096 + boff];
    }
    #pragma unroll
    for (int mi = 0; mi < 4; mi++) {
      int aoff = (wm + mi*16 + lm) * 32 + quad * 8;
      a[mi][0] = *(const v8h*)&As[aoff];
      if (PL == 2) a[mi][1] = *(const v8h*)&As[4096 + aoff];
    }
    #pragma unroll
    for (int mi = 0; mi < 4; mi++) {
      #pragma unroll
      for (int ni = 0; ni < 4; ni++) {
        v4f c0 = acc[mi][ni];
        c0 = __builtin_amdgcn_mfma_f32_16x16x32_f16(a[mi][0], b[ni][0], c0, 0, 0, 0);
        if (PL == 2) {
          c0 = __builtin_amdgcn_mfma_f32_16x16x32_f16(a[mi][0], b[ni][1], c0, 0, 0, 0);
          c0 = __builtin_amdgcn_mfma_f32_16x16x32_f16(a[mi][1], b[ni][0], c0, 0, 0, 0);
          c0 = __builtin_amdgcn_mfma_f32_16x16x32_f16(a[mi][1], b[ni][1], c0, 0, 0, 0);
        }
        acc[mi][ni] = c0;
      }
    }
    __syncthreads();
  }

  float* Cf = (float*)Cv;
  _Float16* Ch = (_Float16*)Cv;
  const size_t cplane = (size_t)M * N;
  #pragma unroll
  for (int mi = 0; mi < 4; mi++) {
    int rbase = m0 + wm + mi*16 + quad*4;
    #pragma unroll
    for (int ni = 0; ni < 4; ni++) {
      int col = n0 + wn + ni*16 + lm;
      float bv = BIAS ? bias[col] : 0.0f;
      #pragma unroll
      for (int r = 0; r < 4; r++) {
        float val = acc[mi][ni][r] * DSCF + bv;
        if (RELU) val = fmaxf(val, 0.0f);
        size_t off = (size_t)(rbase + r) * N + col;
        if (CMODE == 0) Cf[off] = val;
        else if (CMODE == 1) Cf[off] += val;
        else {
          float s = val * SCF;
          _Float16 h0 = (_Float16)s;
          _Float16 h1 = (_Float16)(s - (float)h0);
          Ch[off] = h0;
          Ch[cplane + off] = h1;
        }
      }
    }
  }
}

// ---------------------------------------------------------------------------
// rot[h][d][r][n] -> rotT[h][2 planes][rcol=r*64+n][d] scaled fp16 split
__global__ __launch_bounds__(256) void rott_kernel(const float* __restrict__ rot,
                                                   _Float16* __restrict__ rotT) {
  int h = blockIdx.x, grp = blockIdx.y;    // dim3(8,8)
  const float* rh = rot + (size_t)h * (DH * RR * 64);
  for (int idx = threadIdx.x; idx < 16*128; idx += 256) {
    int rc = grp*16 + (idx >> 7), d = idx & 127;
    int r = rc >> 6, nn = rc & 63;
    float f = rh[(size_t)d * 128 + r * 64 + nn] * SCF;
    _Float16 h0 = (_Float16)f;
    rotT[(size_t)h*32768 + (size_t)rc*128 + d] = h0;
    rotT[(size_t)h*32768 + 16384 + (size_t)rc*128 + d] = (_Float16)(f - (float)h0);
  }
}

// ---------------------------------------------------------------------------
// bucket via MFMA: rotated = qk_head @ rotT^T, fused argmax epilogue.
// A: qkb fp32 (in-register QUAD split, R4-verified XOR-swizzle staging).
// Each wave's 64 cols = one full hash round -> per-wave argmax, no combine.
__global__ __launch_bounds__(256) void bucket_mfma_kernel(const float* __restrict__ qkb,
                                                          const _Float16* __restrict__ rotT,
                                                          int* __restrict__ ids) {
  __shared__ __align__(16) float Af[128*32];          // 16 KB XOR-swizzled
  __shared__ __align__(16) _Float16 Bs[2*128*32];     // 16 KB
  int mtile = blockIdx.x, bh = blockIdx.y;
  int b = bh >> 3, h = bh & 7;
  int tid = threadIdx.x, lane = tid & 63, wave = tid >> 6;
  int wm = (wave & 1) * 64;
  int r = wave >> 1;                                   // round handled by this wave
  int wn = r * 64;
  int lm = lane & 15, quad = lane >> 4;
  const float* Aq = qkb + ((size_t)b * SS + (size_t)mtile * 128) * DD + h * DH;
  const _Float16* Bq = rotT + (size_t)h * 32768;
  v4f acc[4][4];
  #pragma unroll
  for (int i = 0; i < 4; i++)
    #pragma unroll
    for (int j = 0; j < 4; j++) acc[i][j] = (v4f)0.0f;

  for (int k0 = 0; k0 < 128; k0 += 32) {
    #pragma unroll
    for (int i = 0; i < 8; i++) {
      int c = wave * 8 + i;
      if (c < 16) {
        int slot = c * 64 + lane;
        int row = slot >> 3;
        int c4 = (slot & 7) ^ (row & 7);
        gld16(Aq + (size_t)row * DD + k0 + c4 * 4, (char*)Af + (size_t)c * 1024);
      } else {
        int cb = c - 16;
        int p = cb >> 3, q = cb & 7;
        int row = q * 16 + (lane >> 2), col = (lane & 3) * 8;
        gld16(Bq + (size_t)p * 16384 + (size_t)row * 128 + k0 + col,
              (char*)Bs + (size_t)p * 8192 + (size_t)q * 1024);
      }
    }
    __syncthreads();
    v8h b0[4], b1[4];
    #pragma unroll
    for (int ni = 0; ni < 4; ni++) {
      int boff = (wn + ni*16 + lm) * 32 + quad * 8;
      b0[ni] = *(const v8h*)&Bs[boff];
      b1[ni] = *(const v8h*)&Bs[4096 + boff];
    }
    #pragma unroll
    for (int mi = 0; mi < 4; mi++) {
      int arow = wm + mi*16 + lm;
      int sw = arow & 7;
      float4 fA = *(const float4*)(Af + arow*32 + (((2*quad)     ^ sw) << 2));
      float4 fB = *(const float4*)(Af + arow*32 + (((2*quad + 1) ^ sw) << 2));
      v8h a0, a1;
      float fs[8] = {fA.x*SCF, fA.y*SCF, fA.z*SCF, fA.w*SCF,
                     fB.x*SCF, fB.y*SCF, fB.z*SCF, fB.w*SCF};
      #pragma unroll
      for (int j = 0; j < 8; j++) {
        _Float16 p0 = (_Float16)fs[j];
        a0[j] = p0;
        a1[j] = (_Float16)(fs[j] - (float)p0);
      }
      #pragma unroll
      for (int ni = 0; ni < 4; ni++) {
        v4f c0 = acc[mi][ni];
        c0 = __builtin_amdgcn_mfma_f32_16x16x32_f16(a0, b0[ni], c0, 0, 0, 0);
        c0 = __builtin_amdgcn_mfma_f32_16x16x32_f16(a0, b1[ni], c0, 0, 0, 0);
        c0 = __builtin_amdgcn_mfma_f32_16x16x32_f16(a1, b0[ni], c0, 0, 0, 0);
        c0 = __builtin_amdgcn_mfma_f32_16x16x32_f16(a1, b1[ni], c0, 0, 0, 0);
        acc[mi][ni] = c0;
      }
    }
    __syncthreads();
  }

  // argmax epilogue (scaled values; comparisons scale-invariant)
  #pragma unroll
  for (int mi = 0; mi < 4; mi++) {
    #pragma unroll
    for (int rr = 0; rr < 4; rr++) {
      float mx = acc[mi][0][rr]; int xi = lm;
      float mn = acc[mi][0][rr]; int ni_ = lm;
      #pragma unroll
      for (int ni = 1; ni < 4; ni++) {
        float vv = acc[mi][ni][rr];
        int col = ni*16 + lm;
        if (vv > mx) { mx = vv; xi = col; }
        if (vv < mn) { mn = vv; ni_ = col; }
      }
      #pragma unroll
      for (int o = 1; o < 16; o <<= 1) {
        float ox = __shfl_xor(mx, o); int oxi = __shfl_xor(xi, o);
        if (ox > mx || (ox == mx && oxi < xi)) { mx = ox; xi = oxi; }
        float on = __shfl_xor(mn, o); int oni = __shfl_xor(ni_, o);
        if (on < mn || (on == mn && oni < ni_)) { mn = on; ni_ = oni; }
      }
      if (lm == 0) {
        int bi = (mx >= -mn) ? xi : 64 + ni_;
        int s = mtile*128 + wm + mi*16 + quad*4 + rr;
        ids[((size_t)bh * RR + r) * SS + s] = bi + r * NBUCK;
      }
    }
  }
}

// ---------------------------------------------------------------------------
// Parallel stable counting sort (R5-verified, bit-exact vs argsort)
__global__ __launch_bounds__(256) void sort_count_kernel(const int* __restrict__ ids,
                                                         int* __restrict__ counts) {
  int w = blockIdx.x * 4 + (threadIdx.x >> 6);
  int lane = threadIdx.x & 63;
  int bhr = w >> 6, seg = w & 63;
  int id = ids[(size_t)bhr * SS + seg * 64 + lane];
  int bin = id & 127;
  unsigned long long eq = ~0ull;
  #pragma unroll
  for (int bit = 0; bit < 7; bit++) {
    unsigned long long bal = __ballot((bin >> bit) & 1);
    eq &= ((bin >> bit) & 1) ? bal : ~bal;
  }
  int rank = __popcll(eq & ((1ull << lane) - 1ull));
  if (rank == 0)
    counts[((size_t)bhr * 64 + seg) * 128 + bin] = __popcll(eq);
}

__global__ __launch_bounds__(128) void sort_prefix_kernel(int* __restrict__ counts) {
  int bhr = blockIdx.x;
  int bin = threadIdx.x;
  int r = bhr & 1;
  int* cp = counts + (size_t)bhr * 64 * 128;
  int total = 0;
  for (int seg = 0; seg < 64; seg++) total += cp[seg * 128 + bin];
  __shared__ int tot[128];
  tot[bin] = total;
  __syncthreads();
  for (int off = 1; off < 128; off <<= 1) {
    int t = (bin >= off) ? tot[bin - off] : 0;
    __syncthreads();
    tot[bin] += t;
    __syncthreads();
  }
  int run = tot[bin] - total + r * SS;
  for (int seg = 0; seg < 64; seg++) {
    int c = cp[seg * 128 + bin];
    cp[seg * 128 + bin] = run;
    run += c;
  }
}

__global__ __launch_bounds__(256) void sort_scatter_kernel(const int* __restrict__ ids,
                                                           const int* __restrict__ offs,
                                                           int* __restrict__ orig,
                                                           int* __restrict__ undo) {
  int w = blockIdx.x * 4 + (threadIdx.x >> 6);
  int lane = threadIdx.x & 63;
  int bhr = w >> 6, seg = w & 63;
  int s = seg * 64 + lane;
  int id = ids[(size_t)bhr * SS + s];
  int bin = id & 127;
  unsigned long long eq = ~0ull;
  #pragma unroll
  for (int bit = 0; bit < 7; bit++) {
    unsigned long long bal = __ballot((bin >> bit) & 1);
    eq &= ((bin >> bit) & 1) ? bal : ~bal;
  }
  int rank = __popcll(eq & ((1ull << lane) - 1ull));
  int o = offs[((size_t)bhr * 64 + seg) * 128 + bin] + rank;
  int bh = bhr >> 1, r = bhr & 1;
  orig[(size_t)bh * RS + o] = s;
  undo[(size_t)bh * RS + r * SS + s] = o;
}

// ---------------------------------------------------------------------------
__global__ __launch_bounds__(256) void rnorm_kernel(const float* __restrict__ qk,
                                                    const int* __restrict__ orig,
                                                    float* __restrict__ rno) {
  int idx = blockIdx.x * 4 + (threadIdx.x >> 6);
  int lane = threadIdx.x & 63;
  int bh = idx >> 13;
  int k = idx & (RS - 1);
  int b = bh >> 3, h = bh & 7;
  int s = orig[(size_t)bh * RS + k];
  const float* row = qk + ((size_t)(b * SS + s)) * DD + h * DH;
  float x0 = row[lane], x1 = row[lane + 64];
  float ss = x0 * x0 + x1 * x1;
  #pragma unroll
  for (int o = 1; o < 64; o <<= 1) ss += __shfl_xor(ss, o);
  if (lane == 0)
    rno[(size_t)bh * RS + k] = rsqrtf(ss * (1.0f / DH) + 1e-6f) * 0.08838834764831845f;
}

// ---------------------------------------------------------------------------
// MFMA chunked attention. Q/K/V gathered fp32 -> scaled fp16 PL-plane split.
// PL=2 (layer 0): fp32-equivalent QUAD; PL=1 (layer 1): single product.
// LDS: QP (Q then P) [PL][64][136]; KV (K 32-key groups then V [128][36]).
template<int PL>
__global__ __launch_bounds__(256) void attn_mfma_kernel(const float* __restrict__ qk,
                                                        const float* __restrict__ v,
                                                        const int* __restrict__ orig,
                                                        const float* __restrict__ rno,
                                                        float* __restrict__ osort,
                                                        float* __restrict__ lg) {
  __shared__ __align__(16) char smem[34816 + 18432 + 1024];
  _Float16* QP = (_Float16*)smem;                       // [PL][64][136]
  _Float16* KV = (_Float16*)(smem + 34816);             // K: [PL][32][136] / V: [PL][128][36]
  int* kp_lds = (int*)(smem + 34816 + 18432);
  int* qp_lds = kp_lds + 128;
  const int QPs = 64*136, Kps = 32*136, Vps = 128*36;

  int blk = blockIdx.x;
  int n = blk & (NC - 1), bh = blk >> 7;
  int b = bh >> 3, h = bh & 7;
  int pn = (n + NC - 1) & (NC - 1);
  int tid = threadIdx.x, lane = tid & 63, wave = tid >> 6;
  int lm = lane & 15, quad = lane >> 4;
  const int* origp = orig + (size_t)bh * RS;
  const float* rnp = rno + (size_t)bh * RS;
  const size_t base = (size_t)b * SS * DD + (size_t)h * DH;

  // stage Q (scaled split) + key/query positions
  for (int idx = tid; idx < 64*32; idx += 256) {
    int q = idx >> 5, d4 = idx & 31;
    float4 f = *(const float4*)(qk + base + (size_t)origp[n*64+q]*DD + d4*4);
    f.x *= SCF; f.y *= SCF; f.z *= SCF; f.w *= SCF;
    v4h h0; h0[0]=(_Float16)f.x; h0[1]=(_Float16)f.y; h0[2]=(_Float16)f.z; h0[3]=(_Float16)f.w;
    *(v4h*)(QP + q*136 + d4*4) = h0;
    if (PL == 2) {
      v4h h1; h1[0]=(_Float16)(f.x-(float)h0[0]); h1[1]=(_Float16)(f.y-(float)h0[1]);
      h1[2]=(_Float16)(f.z-(float)h0[2]); h1[3]=(_Float16)(f.w-(float)h0[3]);
      *(v4h*)(QP + QPs + q*136 + d4*4) = h1;
    }
  }
  if (tid < 128) kp_lds[tid] = origp[(tid < 64) ? (pn*64 + tid) : (n*64 + tid - 64)];
  else if (tid < 192) qp_lds[tid - 128] = origp[n*64 + tid - 128];

  v4f sc[8];
  #pragma unroll
  for (int j = 0; j < 8; j++) sc[j] = (v4f)0.0f;

  // --- scores: 4 key-groups of 32 ---
  #pragma unroll
  for (int g = 0; g < 4; g++) {
    __syncthreads();
    for (int idx = tid; idx < 32*32; idx += 256) {
      int key = idx >> 5, d4 = idx & 31;
      int kidx = ((g < 2) ? (pn*64 + g*32) : (n*64 + (g-2)*32)) + key;
      float rn = rnp[kidx] * SCF;
      float4 f = *(const float4*)(qk + base + (size_t)origp[kidx]*DD + d4*4);
      f.x *= rn; f.y *= rn; f.z *= rn; f.w *= rn;
      v4h h0; h0[0]=(_Float16)f.x; h0[1]=(_Float16)f.y; h0[2]=(_Float16)f.z; h0[3]=(_Float16)f.w;
      *(v4h*)(KV + key*136 + d4*4) = h0;
      if (PL == 2) {
        v4h h1; h1[0]=(_Float16)(f.x-(float)h0[0]); h1[1]=(_Float16)(f.y-(float)h0[1]);
        h1[2]=(_Float16)(f.z-(float)h0[2]); h1[3]=(_Float16)(f.w-(float)h0[3]);
        *(v4h*)(KV + Kps + key*136 + d4*4) = h1;
      }
    }
    __syncthreads();
    #pragma unroll
    for (int ni = 0; ni < 2; ni++) {
      v4f c0 = sc[g*2 + ni];
      #pragma unroll
      for (int ks = 0; ks < 4; ks++) {
        v8h a0 = *(const v8h*)(QP + (wave*16 + lm)*136 + ks*32 + quad*8);
        v8h b0 = *(const v8h*)(KV + (ni*16 + lm)*136 + ks*32 + quad*8);
        c0 = __builtin_amdgcn_mfma_f32_16x16x32_f16(a0, b0, c0, 0, 0, 0);
        if (PL == 2) {
          v8h a1 = *(const v8h*)(QP + QPs + (wave*16 + lm)*136 + ks*32 + quad*8);
          v8h b1 = *(const v8h*)(KV + Kps + (ni*16 + lm)*136 + ks*32 + quad*8);
          c0 = __builtin_amdgcn_mfma_f32_16x16x32_f16(a0, b1, c0, 0, 0, 0);
          c0 = __builtin_amdgcn_mfma_f32_16x16x32_f16(a1, b0, c0, 0, 0, 0);
          c0 = __builtin_amdgcn_mfma_f32_16x16x32_f16(a1, b1, c0, 0, 0, 0);
        }
      }
      sc[g*2 + ni] = c0;
    }
  }
  __syncthreads();   // all score MFMAs done; QP becomes P

  int kp_l[8];
  #pragma unroll
  for (int j = 0; j < 8; j++) kp_l[j] = kp_lds[j*16 + lm];

  // --- masked softmax per row; write scaled-split probs into QP ---
  #pragma unroll
  for (int rr = 0; rr < 4; rr++) {
    int row = wave*16 + quad*4 + rr;
    int qp = qp_lds[row];
    float sv[8];
    #pragma unroll
    for (int j = 0; j < 8; j++) {
      float s = sc[j][rr] * DSCF;
      int kp = kp_l[j];
      sv[j] = (kp > qp) ? -1000000000.0f : ((kp == qp) ? -100000.0f : s);
    }
    float m = sv[0];
    #pragma unroll
    for (int j = 1; j < 8; j++) m = fmaxf(m, sv[j]);
    #pragma unroll
    for (int o = 1; o < 16; o <<= 1) m = fmaxf(m, __shfl_xor(m, o));
    float es[8], S = 0.0f;
    #pragma unroll
    for (int j = 0; j < 8; j++) { es[j] = __expf(sv[j] - m); S += es[j]; }
    #pragma unroll
    for (int o = 1; o < 16; o <<= 1) S += __shfl_xor(S, o);
    float inv = 1.0f / S;
    if (lm == 0) lg[(size_t)bh * RS + n*64 + row] = m + __logf(S);
    #pragma unroll
    for (int j = 0; j < 8; j++) {
      float p = es[j] * inv * SCF;
      _Float16 p0 = (_Float16)p;
      QP[row*136 + j*16 + lm] = p0;
      if (PL == 2) QP[QPs + row*136 + j*16 + lm] = (_Float16)(p - (float)p0);
    }
  }

  // --- PV: 4 key-groups, V transposed into [d][key] (stride 36) ---
  v4f oacc[8];
  #pragma unroll
  for (int j = 0; j < 8; j++) oacc[j] = (v4f)0.0f;
  #pragma unroll
  for (int g = 0; g < 4; g++) {
    __syncthreads();   // P visible (g=0) / prev V readers done
    for (int idx = tid; idx < 32*32; idx += 256) {
      int key = idx >> 5, d4 = idx & 31;
      int kidx = ((g < 2) ? (pn*64 + g*32) : (n*64 + (g-2)*32)) + key;
      float4 f = *(const float4*)(v + base + (size_t)origp[kidx]*DD + d4*4);
      float fs[4] = {f.x*SCF, f.y*SCF, f.z*SCF, f.w*SCF};
      #pragma unroll
      for (int j = 0; j < 4; j++) {
        int d = d4*4 + j;
        _Float16 p0 = (_Float16)fs[j];
        KV[d*36 + key] = p0;
        if (PL == 2) KV[Vps + d*36 + key] = (_Float16)(fs[j] - (float)p0);
      }
    }
    __syncthreads();
    v8h a0 = *(const v8h*)(QP + (wave*16 + lm)*136 + g*32 + quad*8);
    v8h a1;
    if (PL == 2) a1 = *(const v8h*)(QP + QPs + (wave*16 + lm)*136 + g*32 + quad*8);
    #pragma unroll
    for (int dn = 0; dn < 8; dn++) {
      v4h lo0 = *(const v4h*)(KV + (dn*16 + lm)*36 + quad*8);
      v4h hi0 = *(const v4h*)(KV + (dn*16 + lm)*36 + quad*8 + 4);
      v8h b0 = __builtin_shufflevector(lo0, hi0, 0,1,2,3,4,5,6,7);
      v4f c0 = oacc[dn];
      c0 = __builtin_amdgcn_mfma_f32_16x16x32_f16(a0, b0, c0, 0, 0, 0);
      if (PL == 2) {
        v4h lo1 = *(const v4h*)(KV + Vps + (dn*16 + lm)*36 + quad*8);
        v4h hi1 = *(const v4h*)(KV + Vps + (dn*16 + lm)*36 + quad*8 + 4);
        v8h b1 = __builtin_shufflevector(lo1, hi1, 0,1,2,3,4,5,6,7);
        c0 = __builtin_amdgcn_mfma_f32_16x16x32_f16(a0, b1, c0, 0, 0, 0);
        c0 = __builtin_amdgcn_mfma_f32_16x16x32_f16(a1, b0, c0, 0, 0, 0);
        c0 = __builtin_amdgcn_mfma_f32_16x16x32_f16(a1, b1, c0, 0, 0, 0);
      }
      oacc[dn] = c0;
    }
  }

  // epilogue: O -> osort fp32
  #pragma unroll
  for (int dn = 0; dn < 8; dn++) {
    #pragma unroll
    for (int rr = 0; rr < 4; rr++) {
      int row = wave*16 + quad*4 + rr;
      osort[((size_t)bh * RS + n*64 + row) * DH + dn*16 + lm] = oacc[dn][rr] * DSCF;
    }
  }
}

// ---------------------------------------------------------------------------
// unsort + round-combine -> scaled fp16 2-plane split in h region
__global__ __launch_bounds__(256) void unsort_split_kernel(const float* __restrict__ osort,
                                                           const float* __restrict__ lg,
                                                           const int* __restrict__ undo,
                                                           _Float16* __restrict__ attn) {
  int gid = blockIdx.x * 4 + (threadIdx.x >> 6);
  int lane = threadIdx.x & 63;
  int bh = gid >> 12;
  int s = gid & (SS - 1);
  int b = bh >> 3, h = bh & 7;
  int k0 = undo[(size_t)bh * RS + s];
  int k1 = undo[(size_t)bh * RS + SS + s];
  float l0 = lg[(size_t)bh * RS + k0], l1 = lg[(size_t)bh * RS + k1];
  float m = fmaxf(l0, l1);
  float e0 = __expf(l0 - m), e1 = __expf(l1 - m);
  float inv = 1.0f / (e0 + e1);
  float w0 = e0 * inv, w1 = e1 * inv;
  const float* r0 = osort + ((size_t)bh * RS + k0) * DH;
  const float* r1 = osort + ((size_t)bh * RS + k1) * DH;
  const size_t PLN = (size_t)MROWS * DD;
  _Float16* outp = attn + ((size_t)(b * SS + s)) * DD + h * DH;
  float sA = (w0 * r0[lane]      + w1 * r1[lane])      * SCF;
  float sB = (w0 * r0[lane + 64] + w1 * r1[lane + 64]) * SCF;
  _Float16 a0 = (_Float16)sA, b0 = (_Float16)sB;
  outp[lane] = a0;                 outp[lane + 64] = b0;
  outp[PLN + lane] = (_Float16)(sA - (float)a0);
  outp[PLN + lane + 64] = (_Float16)(sB - (float)b0);
}

// ---------------------------------------------------------------------------
__global__ __launch_bounds__(256) void softmax_b_kernel(const float* __restrict__ logits,
                                                        const float* __restrict__ bout,
                                                        float* __restrict__ out) {
  int i = blockIdx.x * 256 + threadIdx.x;
  if (i >= SS * VV) return;
  int s = i / VV, vv = i - s * VV;
  float bvv = bout[vv];
  float l0 = logits[(size_t)s * VP + vv] + bvv;
  float l1 = logits[(size_t)(SS + s) * VP + vv] + bvv;
  float m = fmaxf(l0, l1);
  float e0 = __expf(l0 - m), e1 = __expf(l1 - m);
  float inv = 1.0f / (e0 + e1);
  out[(size_t)s * VV + vv] = e0 * inv;
  out[(size_t)(SS + s) * VV + vv] = e1 * inv;
}

// ---------------------------------------------------------------------------
// Workspace: extent 237,502,464 B (proven). pool[2NX..4NX) = osort region,
// time-shared: weights wt at +0, counts at +8MB, rotT at +10MB — all dead
// before attn writes osort and before FFN reuses [0,16MB).
extern "C" void kernel_launch(void* const* d_in, const int* in_sizes, int n_in,
                              void* d_out, int out_size, void* d_ws, size_t ws_size,
                              hipStream_t stream) {
  (void)in_sizes; (void)n_in; (void)out_size; (void)ws_size;
  const float* x     = (const float*)d_in[0];
  const float* ln1_g = (const float*)d_in[1];
  const float* ln1_b = (const float*)d_in[2];
  const float* Wqk   = (const float*)d_in[3];
  const float* Wv    = (const float*)d_in[4];
  const float* Wo    = (const float*)d_in[5];
  const float* rot   = (const float*)d_in[6];
  const float* ln2_g = (const float*)d_in[7];
  const float* ln2_b = (const float*)d_in[8];
  const float* W1    = (const float*)d_in[9];
  const float* b1    = (const float*)d_in[10];
  const float* W2    = (const float*)d_in[11];
  const float* b2    = (const float*)d_in[12];
  const float* lnf_g = (const float*)d_in[13];
  const float* lnf_b = (const float*)d_in[14];
  const float* Wout  = (const float*)d_in[15];
  const float* bout  = (const float*)d_in[16];

  const size_t NX = (size_t)MROWS * DD;            // 8,388,608
  float* x1 = (float*)d_ws;
  float* x2 = x1 + NX;
  float* h  = x2 + NX;
  _Float16* hs = (_Float16*)h;                     // [2][M][1024] fp16
  float* pool = h + NX;
  float* qkb   = pool;
  float* vb    = pool + NX;
  float* osort = pool + 2*NX;
  _Float16* ffh = (_Float16*)pool;                 // [2][M][2048] fp16
  _Float16* hcs = (_Float16*)pool;                 // head phase
  char* wbase = (char*)(pool + 2*NX);
  _Float16* wt = (_Float16*)wbase;                 // weight squat region
  int* counts = (int*)(wbase + (8u<<20));          // 1 MB
  _Float16* rotTs = (_Float16*)(wbase + (10u<<20));// 512 KB
  float* after = pool + 4*NX;
  float* lgb = after;
  float* rno = lgb + (size_t)BH * RS;
  int* orig = (int*)(rno + (size_t)BH * RS);
  int* undo = orig + (size_t)BH * RS;
  int* ids  = undo + (size_t)BH * RS;
  float* logitsP = h;                              // head phase

  const size_t AP_D  = NX;
  const size_t AP_FF = (size_t)MROWS * 2048;
  const size_t BP_D  = (size_t)DD * DD;
  const size_t BP_W1 = (size_t)2048 * DD;
  const size_t BP_W2 = (size_t)DD * 2048;
  const size_t BP_HD = (size_t)VP * 2048;

  init_x_kernel<<<(int)(NX / 256), 256, 0, stream>>>(x, x1, x2);

  for (int l = 0; l < LL; l++) {
    // --- attention ---
    ln_split_kernel<<<MROWS, 256, 0, stream>>>(x2, ln1_g + l*DD, ln1_b + l*DD, hs);

    wconv_kernel<<<dim3(32, 32), 256, 0, stream>>>(Wqk + (size_t)l*DD*DD, wt, DD, DD, DD, DD);
    qgemm_kernel<2,0,false,false><<<dim3(8, 64), 256, 0, stream>>>(
        hs, wt, nullptr, qkb, MROWS, DD, DD, AP_D, BP_D);

    wconv_kernel<<<dim3(32, 32), 256, 0, stream>>>(Wv + (size_t)l*DD*DD, wt, DD, DD, DD, DD);
    if (l == 0)
      qgemm_kernel<2,0,false,false><<<dim3(8, 64), 256, 0, stream>>>(
          hs, wt, nullptr, vb, MROWS, DD, DD, AP_D, BP_D);
    else
      qgemm_kernel<1,0,false,false><<<dim3(8, 64), 256, 0, stream>>>(
          hs, wt, nullptr, vb, MROWS, DD, DD, AP_D, BP_D);

    rott_kernel<<<dim3(8, 8), 256, 0, stream>>>(rot + (size_t)l*HH*DH*RR*64, rotTs);
    bucket_mfma_kernel<<<dim3(32, 16), 256, 0, stream>>>(qkb, rotTs, ids);

    hipMemsetAsync(counts, 0, (size_t)BH * RR * 64 * 128 * sizeof(int), stream);
    sort_count_kernel<<<512, 256, 0, stream>>>(ids, counts);
    sort_prefix_kernel<<<BH*RR, 128, 0, stream>>>(counts);
    sort_scatter_kernel<<<512, 256, 0, stream>>>(ids, counts, orig, undo);

    rnorm_kernel<<<BH*RS/4, 256, 0, stream>>>(qkb, orig, rno);
    if (l == 0)
      attn_mfma_kernel<2><<<BH*NC, 256, 0, stream>>>(qkb, vb, orig, rno, osort, lgb);
    else
      attn_mfma_kernel<1><<<BH*NC, 256, 0, stream>>>(qkb, vb, orig, rno, osort, lgb);
    unsort_split_kernel<<<BH*SS/4, 256, 0, stream>>>(osort, lgb, undo, hs);   // osort dead

    wconv_kernel<<<dim3(32, 32), 256, 0, stream>>>(Wo + (size_t)l*DD*DD, wt, DD, DD, DD, DD);
    if (l == 0)
      qgemm_kernel<2,1,false,false><<<dim3(8, 64), 256, 0, stream>>>(
          hs, wt, nullptr, x1, MROWS, DD, DD, AP_D, BP_D);
    else
      qgemm_kernel<1,1,false,false><<<dim3(8, 64), 256, 0, stream>>>(
          hs, wt, nullptr, x1, MROWS, DD, DD, AP_D, BP_D);

    // --- FFN, two FF-halves of 2048 ---
    ln_split_kernel<<<MROWS, 256, 0, stream>>>(x1, ln2_g + l*DD, ln2_b + l*DD, hs);
    for (int hf = 0; hf < 2; hf++) {
      const float* W1h = W1 + (size_t)l*DD*FFD + (size_t)hf*2048;
      const float* W2h = W2 + (size_t)l*FFD*DD + (size_t)hf*2048*DD;
      _Float16* wt1 = wt;
      _Float16* wt2 = wt + 2u*2097152u;
      wconv_kernel<<<dim3(64, 32), 256, 0, stream>>>(W1h, wt1, DD, 2048, 2048, FFD);
      wconv_kernel<<<dim3(32, 64), 256, 0, stream>>>(W2h, wt2, 2048, DD, DD, DD);
      if (l == 0) {
        qgemm_kernel<2,2,true,true><<<dim3(16, 64), 256, 0, stream>>>(
            hs, wt1, b1 + (size_t)l*FFD + hf*2048, ffh, MROWS, 2048, DD, AP_D, BP_W1);
        if (hf == 0)
          qgemm_kernel<2,1,true,false><<<dim3(8, 64), 256, 0, stream>>>(
              ffh, wt2, b2 + (size_t)l*DD, x2, MROWS, DD, 2048, AP_FF, BP_W2);
        else
          qgemm_kernel<2,1,false,false><<<dim3(8, 64), 256, 0, stream>>>(
              ffh, wt2, nullptr, x2, MROWS, DD, 2048, AP_FF, BP_W2);
      } else {
        qgemm_kernel<1,2,true,true><<<dim3(16, 64), 256, 0, stream>>>(
            hs, wt1, b1 + (size_t)l*FFD + hf*2048, ffh, MROWS, 2048, DD, AP_D, BP_W1);
        if (hf == 0)
          qgemm_kernel<1,1,true,false><<<dim3(8, 64), 256, 0, stream>>>(
              ffh, wt2, b2 + (size_t)l*DD, x2, MROWS, DD, 2048, AP_FF, BP_W2);
        else
          qgemm_kernel<1,1,false,false><<<dim3(8, 64), 256, 0, stream>>>(
              ffh, wt2, nullptr, x2, MROWS, DD, 2048, AP_FF, BP_W2);
      }
    }
  }

  // --- head ---
  ln_concat_split_kernel<<<MROWS, 256, 0, stream>>>(x1, x2, lnf_g, lnf_b, hcs);
  wconv_kernel<<<dim3(12, 64), 256, 0, stream>>>(Wout, wt, 2*DD, VV, VP, VV);
  qgemm_kernel<1,0,false,false><<<dim3(3, 64), 256, 0, stream>>>(
      hcs, wt, nullptr, logitsP, MROWS, VP, 2*DD, AP_FF, BP_HD);
  softmax_b_kernel<<<(SS*VV + 255)/256, 256, 0, stream>>>(logitsP, bout, (float*)d_out);
}